// Round 2
// 643.758 us; speedup vs baseline: 1.0660x; 1.0660x over previous
//
#include <hip/hip_runtime.h>
#include <math.h>

typedef _Float16 half8 __attribute__((ext_vector_type(8)));
typedef __fp16 fp16x2 __attribute__((ext_vector_type(2)));
typedef float floatx4 __attribute__((ext_vector_type(4)));

constexpr float C_SS16 = 0.04419417382415922f;  // i2/16
constexpr float C_UNI  = 0.05103103630798288f;  // i3/sqrt(128)
constexpr float C2_SS  = 0.0625f;               // i2/sqrt(128)
constexpr float C2_VS  = 0.07216878364870323f;  // i3/8
constexpr float C_LS   = 0.17677669529663687f;  // 1/sqrt(32)
constexpr float C_LV   = 0.25f;                 // 1/sqrt(16)
constexpr float RS     = 2048.0f;               // residual scale (keeps lo-parts normal in fp16)
constexpr float RSI    = 1.0f / 2048.0f;

// wave-local LDS fence: all shared buffers are per-wave, so a full
// __syncthreads (vmcnt(0) drain + 4-wave rendezvous) is never needed.
#define LDS_FENCE() asm volatile("s_waitcnt lgkmcnt(0)" ::: "memory")

// split fp32 -> fp16 hi (RTZ, packed) + SCALED fp16 residual.
// (float)RTZ16(p) == p & 0xFFFFE000 for f16-normal-range p; the sub-normal
// mismatch is ~2^-24 absolute -> negligible vs the 2^-22 split target.
__device__ __forceinline__ void split8s(const float* p, half8& ah, half8& alS) {
#pragma unroll
    for (int j = 0; j < 8; j += 2) {
        fp16x2 h = __builtin_amdgcn_cvt_pkrtz(p[j], p[j+1]);
        const float b0 = __uint_as_float(__float_as_uint(p[j])   & 0xFFFFE000u);
        const float b1 = __uint_as_float(__float_as_uint(p[j+1]) & 0xFFFFE000u);
        fp16x2 l = __builtin_amdgcn_cvt_pkrtz((p[j] - b0) * RS, (p[j+1] - b1) * RS);
        ah[j] = (_Float16)h[0]; ah[j+1] = (_Float16)h[1];
        alS[j] = (_Float16)l[0]; alS[j+1] = (_Float16)l[1];
    }
}
// 3-term split MFMA with separate scaled-residual accumulator
__device__ __forceinline__ void mfma_tri(half8 ah, half8 alS, half8 bh, half8 blS,
                                         floatx4& acc, floatx4& accR) {
    acc  = __builtin_amdgcn_mfma_f32_16x16x32_f16(ah,  bh,  acc,  0, 0, 0);
    accR = __builtin_amdgcn_mfma_f32_16x16x32_f16(alS, bh,  accR, 0, 0, 0);
    accR = __builtin_amdgcn_mfma_f32_16x16x32_f16(ah,  blS, accR, 0, 0, 0);
}

// =====================================================================
// Weight prep: fp32 -> (fp16 hi, fp16 lo*2048) B-fragments, norms folded.
// Grid-stride over many blocks (was single-block = 1 CU latency-bound).
// =====================================================================
__global__ void prep_w(const float* __restrict__ W1ss, const float* __restrict__ W1sv,
                       const float* __restrict__ W1vs, const float* __restrict__ W1vvs,
                       const float* __restrict__ W1vvv,
                       const float* __restrict__ W2ss, const float* __restrict__ W2sv,
                       const float* __restrict__ W2vs, const float* __restrict__ W2vvs,
                       const float* __restrict__ W2vvv,
                       const float* __restrict__ W3ss, const float* __restrict__ W3sv,
                       const float* __restrict__ W3vs, const float* __restrict__ W3vvs,
                       const float* __restrict__ W3vvv,
                       _Float16* B1sh, _Float16* B1sl, _Float16* B1vh, _Float16* B1vl,
                       _Float16* B2sh, _Float16* B2sl, _Float16* B2vh, _Float16* B2vl,
                       _Float16* B3sh, _Float16* B3sl, _Float16* B3vh, _Float16* B3vl)
{
    const int t0 = blockIdx.x*256 + threadIdx.x;
    const int gs = gridDim.x*256;
    // B1s: Tk=10, K=320 (256 ss + 64 vvs), 16 cols
    for (int idx = t0; idx < 10*512; idx += gs) {
        int t_k = idx >> 9, lane = (idx >> 3) & 63, j = idx & 7;
        int q = lane >> 4, n = lane & 15;
        int k = t_k*32 + q*8 + j;
        float v;
        if (k < 256) { int i = k>>4, jj = k&15; v = W1ss[(i*16+jj)*16+n] * C_SS16; }
        else { int kk = k-256; int i = kk>>3, jj = kk&7; v = W1vvs[(i*8+jj)*16+n] * C_UNI; }
        _Float16 h = (_Float16)v;
        B1sh[idx] = h; B1sl[idx] = (_Float16)((v - (float)h) * RS);
    }
    // B1v: Tk=10, K=320 (128 sv + 128 vs + 64 vvv), 8 cols (8..15 zero)
    for (int idx = t0; idx < 10*512; idx += gs) {
        int t_k = idx >> 9, lane = (idx >> 3) & 63, j = idx & 7;
        int q = lane >> 4, n = lane & 15;
        int k = t_k*32 + q*8 + j;
        float v = 0.f;
        if (n < 8) {
            if (k < 128) { int i = k>>3, jj = k&7; v = W1sv[(i*8+jj)*8+n] * C_UNI; }
            else if (k < 256) { int kk = k-128; int i = kk>>4, jj = kk&15; v = W1vs[(i*16+jj)*8+n] * C_UNI; }
            else { int kk = k-256; int i = kk>>3, jj = kk&7; v = W1vvv[(i*8+jj)*8+n] * C_UNI; }
        }
        _Float16 h = (_Float16)v;
        B1vh[idx] = h; B1vl[idx] = (_Float16)((v - (float)h) * RS);
    }
    // B2s: Tn=3, Tk=6, K=192 (128 ss + 64 vvs), 48 cols
    for (int idx = t0; idx < 3*6*512; idx += gs) {
        int tn = idx / 3072, t_k = (idx % 3072) >> 9, lane = (idx >> 3) & 63, j = idx & 7;
        int q = lane >> 4, n = lane & 15, col = tn*16 + n;
        int k = t_k*32 + q*8 + j;
        float v;
        if (k < 128) { int i = k>>3, jj = k&7; v = W2ss[(i*8+jj)*48+col] * C2_SS; }
        else { int kk = k-128; int i = kk>>3, jj = kk&7; v = W2vvs[(i*8+jj)*48+col] * C_UNI; }
        _Float16 h = (_Float16)v;
        B2sh[idx] = h; B2sl[idx] = (_Float16)((v - (float)h) * RS);
    }
    // B2v: Tk=8, K=256 (128 sv + 64 vs + 64 vvv), 16 cols
    for (int idx = t0; idx < 8*512; idx += gs) {
        int t_k = idx >> 9, lane = (idx >> 3) & 63, j = idx & 7;
        int q = lane >> 4, n = lane & 15;
        int k = t_k*32 + q*8 + j;
        float v;
        if (k < 128) { int i = k>>3, jj = k&7; v = W2sv[(i*8+jj)*16+n] * C_UNI; }
        else if (k < 192) { int kk = k-128; int i = kk>>3, jj = kk&7; v = W2vs[(i*8+jj)*16+n] * C2_VS; }
        else { int kk = k-192; int i = kk>>3, jj = kk&7; v = W2vvv[(i*8+jj)*16+n] * C_UNI; }
        _Float16 h = (_Float16)v;
        B2vh[idx] = h; B2vl[idx] = (_Float16)((v - (float)h) * RS);
    }
    // B3s: Tn=3, Tk=10, K=320 (256 ss + 64 vvs), 48 cols
    for (int idx = t0; idx < 3*10*512; idx += gs) {
        int tn = idx / 5120, rem = idx % 5120;
        int t_k = rem >> 9, lane = (rem >> 3) & 63, j = rem & 7;
        int q = lane >> 4, n = lane & 15, col = tn*16 + n;
        int k = t_k*32 + q*8 + j;
        float v;
        if (k < 256) { int i = k>>4, jj = k&15; v = W3ss[(i*16+jj)*48+col] * C_SS16; }
        else { int kk = k-256; int i = kk>>3, jj = kk&7; v = W3vvs[(i*8+jj)*48+col] * C_UNI; }
        _Float16 h = (_Float16)v;
        B3sh[idx] = h; B3sl[idx] = (_Float16)((v - (float)h) * RS);
    }
    // B3v: Tk=10, K=320 (128 sv + 128 vs + 64 vvv), 16 cols
    for (int idx = t0; idx < 10*512; idx += gs) {
        int t_k = idx >> 9, lane = (idx >> 3) & 63, j = idx & 7;
        int q = lane >> 4, n = lane & 15;
        int k = t_k*32 + q*8 + j;
        float v;
        if (k < 128) { int i = k>>3, jj = k&7; v = W3sv[(i*8+jj)*16+n] * C_UNI; }
        else if (k < 256) { int kk = k-128; int i = kk>>4, jj = kk&15; v = W3vs[(i*16+jj)*16+n] * C_UNI; }
        else { int kk = k-256; int i = kk>>3, jj = kk&7; v = W3vvv[(i*8+jj)*16+n] * C_UNI; }
        _Float16 h = (_Float16)v;
        B3vh[idx] = h; B3vl[idx] = (_Float16)((v - (float)h) * RS);
    }
}

// =====================================================================
// Fused edge kernel: stage1 MFMA -> LDS transpose -> stage2 MFMA -> gate
// -> linear -> m2h[rank[e]][40] fp32 messages (CSR-permuted so agg_k
// streams). Wave = 16 edges. No __syncthreads: all LDS is per-wave.
// =====================================================================
__global__ __launch_bounds__(256)
void edge_fused(const float* __restrict__ ns, const float* __restrict__ nv,
                const float* __restrict__ edge_s, const float* __restrict__ edge_v,
                const int* __restrict__ ei, const int* __restrict__ rank,
                const _Float16* __restrict__ B1sh, const _Float16* __restrict__ B1sl,
                const _Float16* __restrict__ B1vh, const _Float16* __restrict__ B1vl,
                const _Float16* __restrict__ B2sh, const _Float16* __restrict__ B2sl,
                const _Float16* __restrict__ B2vh, const _Float16* __restrict__ B2vl,
                const float* __restrict__ Lms, const float* __restrict__ Lmv,
                float* __restrict__ m2h, int E)
{
    // per-wave scratch: [0..783] = mT (stride 41, 656 used) then hsL (stride 49);
    // [784..1567] = gvL. mT is dead before hsL overwrites it (WAR fenced).
    __shared__ float buf[4][1568];
    const int lane = threadIdx.x & 63;
    const int wv = threadIdx.x >> 6;
    const int e0 = (blockIdx.x*4 + wv) * 16;
    const int q = lane >> 4, n = lane & 15;
    const int e = min(e0 + n, E - 1);
    const int qh = q >> 1, ql = q & 1;
    const int r = ei[e], c2 = ei[E + e];
    const int slot = rank[e];          // CSR output row for this edge
    float* const mTl = &buf[wv][0];
    float* const hsL = &buf[wv][0];
    float* const gvL = &buf[wv][784];

    // ---------------- stage 1 feature slices ----------------
    float rs_sel[8], rs4[4], rva[2][3], rvs[4][3], csh[8], cv[8][3];
#pragma unroll
    for (int t = 0; t < 8; ++t) rs_sel[t] = ns[(size_t)r*16 + 2*t + qh];
#pragma unroll
    for (int t = 0; t < 4; ++t) rs4[t] = ns[(size_t)r*16 + 4*t + q];
#pragma unroll
    for (int cc = 0; cc < 3; ++cc) {
        rva[0][cc] = nv[(size_t)r*24 + 3*q + cc];
        rva[1][cc] = nv[(size_t)r*24 + 3*(q+4) + cc];
    }
#pragma unroll
    for (int u = 0; u < 4; ++u)
#pragma unroll
        for (int cc = 0; cc < 3; ++cc) rvs[u][cc] = nv[(size_t)r*24 + 3*(2*u+qh) + cc];
    {
        const float4* p = (const float4*)(ns + (size_t)c2*16 + ql*8);
#pragma unroll
        for (int t = 0; t < 2; ++t) { float4 v = p[t]; csh[4*t]=v.x; csh[4*t+1]=v.y; csh[4*t+2]=v.z; csh[4*t+3]=v.w; }
        const float4* pv = (const float4*)(nv + (size_t)c2*24);
        float tmp[24];
#pragma unroll
        for (int t = 0; t < 6; ++t) { float4 v = pv[t]; tmp[4*t]=v.x; tmp[4*t+1]=v.y; tmp[4*t+2]=v.z; tmp[4*t+3]=v.w; }
#pragma unroll
        for (int k = 0; k < 8; ++k) { cv[k][0]=tmp[3*k]; cv[k][1]=tmp[3*k+1]; cv[k][2]=tmp[3*k+2]; }
    }

    const half8* B1sH = (const half8*)B1sh; const half8* B1sL = (const half8*)B1sl;
    const half8* B1vH = (const half8*)B1vh; const half8* B1vL = (const half8*)B1vl;

    // ---- stage1 scalar GEMM: [16e x 320] @ [320 x 16] ----
    {
        floatx4 acc = {0.f,0.f,0.f,0.f}, accR = {0.f,0.f,0.f,0.f};
#pragma unroll
        for (int t = 0; t < 10; ++t) {
            float p[8];
            if (t < 8) {
                const float m = rs_sel[t];
#pragma unroll
                for (int j = 0; j < 8; ++j) p[j] = m * csh[j];
            } else {
                const int u = t - 8;
                const float vx = rva[u][0], vy = rva[u][1], vz = rva[u][2];
#pragma unroll
                for (int j = 0; j < 8; ++j) p[j] = fmaf(vx, cv[j][0], fmaf(vy, cv[j][1], vz*cv[j][2]));
            }
            half8 ah, al; split8s(p, ah, al);
            mfma_tri(ah, al, B1sH[t*64 + lane], B1sL[t*64 + lane], acc, accR);
        }
#pragma unroll
        for (int r2 = 0; r2 < 4; ++r2)
            mTl[(q*4 + r2)*41 + n] = acc[r2] + accR[r2]*RSI;
    }
    // ---- stage1 vector GEMMs per component ----
#pragma unroll 1
    for (int c = 0; c < 3; ++c) {
        const int c1 = (c+1)%3, c2i = (c+2)%3;
        floatx4 acc = {0.f,0.f,0.f,0.f}, accR = {0.f,0.f,0.f,0.f};
#pragma unroll
        for (int t = 0; t < 10; ++t) {
            float p[8];
            if (t < 4) {
                const float m = rs4[t];
#pragma unroll
                for (int j = 0; j < 8; ++j) p[j] = m * cv[j][c];
            } else if (t < 8) {
                const float m = rvs[t-4][c];
#pragma unroll
                for (int j = 0; j < 8; ++j) p[j] = m * csh[j];
            } else {
                const int u = t - 8;
                const float v1 = rva[u][c1], v2 = rva[u][c2i];
#pragma unroll
                for (int j = 0; j < 8; ++j) p[j] = v1*cv[j][c2i] - v2*cv[j][c1];
            }
            half8 ah, al; split8s(p, ah, al);
            mfma_tri(ah, al, B1vH[t*64 + lane], B1vL[t*64 + lane], acc, accR);
        }
        if (n < 8) {
#pragma unroll
            for (int r2 = 0; r2 < 4; ++r2)
                mTl[(q*4 + r2)*41 + 16 + 3*n + c] = acc[r2] + accR[r2]*RSI;
        }
    }
    LDS_FENCE();   // mT writes complete -> wave-local transpose read

    // ---------------- stage 2 inputs ----------------
    float msr[4], mva[2][3], es[8], ev[8][3];
#pragma unroll
    for (int t = 0; t < 4; ++t) msr[t] = mTl[n*41 + 4*t + q];
#pragma unroll
    for (int u = 0; u < 2; ++u)
#pragma unroll
        for (int cc = 0; cc < 3; ++cc) mva[u][cc] = mTl[n*41 + 16 + 3*(4*u+q) + cc];
    {
        const float4* p = (const float4*)(edge_s + (size_t)e*8);
#pragma unroll
        for (int t = 0; t < 2; ++t) { float4 v = p[t]; es[4*t]=v.x; es[4*t+1]=v.y; es[4*t+2]=v.z; es[4*t+3]=v.w; }
        const float4* pv = (const float4*)(edge_v + (size_t)e*24);
        float tmp[24];
#pragma unroll
        for (int t = 0; t < 6; ++t) { float4 v = pv[t]; tmp[4*t]=v.x; tmp[4*t+1]=v.y; tmp[4*t+2]=v.z; tmp[4*t+3]=v.w; }
#pragma unroll
        for (int k = 0; k < 8; ++k) { ev[k][0]=tmp[3*k]; ev[k][1]=tmp[3*k+1]; ev[k][2]=tmp[3*k+2]; }
    }

    const half8* B2sH = (const half8*)B2sh; const half8* B2sL = (const half8*)B2sl;
    const half8* B2vH = (const half8*)B2vh; const half8* B2vL = (const half8*)B2vl;

    // ---- stage2 scalar GEMM: [16e x 192] @ [192 x 48] ----
    floatx4 accs[3], accsR[3];
#pragma unroll
    for (int t = 0; t < 3; ++t) { accs[t] = (floatx4){0.f,0.f,0.f,0.f}; accsR[t] = (floatx4){0.f,0.f,0.f,0.f}; }
#pragma unroll
    for (int t = 0; t < 6; ++t) {
        float p[8];
        if (t < 4) {
            const float m = msr[t];
#pragma unroll
            for (int j = 0; j < 8; ++j) p[j] = m * es[j];
        } else {
            const int u = t - 4;
            const float vx = mva[u][0], vy = mva[u][1], vz = mva[u][2];
#pragma unroll
            for (int j = 0; j < 8; ++j) p[j] = fmaf(vx, ev[j][0], fmaf(vy, ev[j][1], vz*ev[j][2]));
        }
        half8 ah, al; split8s(p, ah, al);
#pragma unroll
        for (int tn = 0; tn < 3; ++tn)
            mfma_tri(ah, al, B2sH[(tn*6 + t)*64 + lane], B2sL[(tn*6 + t)*64 + lane], accs[tn], accsR[tn]);
    }

    LDS_FENCE();   // drain mT reads (WAR: hsL aliases mT region)
#pragma unroll
    for (int t = 0; t < 3; ++t)
#pragma unroll
        for (int r2 = 0; r2 < 4; ++r2) {
            const int row = q*4 + r2;
            const float v = accs[t][r2] + accsR[t][r2]*RSI;
            if (t < 2) hsL[row*49 + t*16 + n] = v / (1.f + __expf(-v)) * C_LS;
            else       hsL[row*49 + 32 + n] = v;
        }
    LDS_FENCE();   // hsL visible to wave

    // scalar epilogue
    {
        float os[4] = {0.f, 0.f, 0.f, 0.f};
#pragma unroll 4
        for (int s = 0; s < 32; ++s) {
            const float hv_ = hsL[n*49 + s];
            const float4 w = *(const float4*)(Lms + s*16 + 4*q);
            os[0] = fmaf(hv_, w.x, os[0]); os[1] = fmaf(hv_, w.y, os[1]);
            os[2] = fmaf(hv_, w.z, os[2]); os[3] = fmaf(hv_, w.w, os[3]);
        }
        if (e0 + n < E) {
#pragma unroll
            for (int u = 0; u < 4; ++u)
                m2h[(size_t)slot*40 + 4*q + u] = os[u];
        }
    }

    // ---- stage2 vector GEMMs ----
    floatx4 accv[3];
#pragma unroll 1
    for (int c = 0; c < 3; ++c) {
        const int c1 = (c+1)%3, c2i = (c+2)%3;
        floatx4 acc = {0.f,0.f,0.f,0.f}, accR = {0.f,0.f,0.f,0.f};
#pragma unroll
        for (int t = 0; t < 8; ++t) {
            float p[8];
            if (t < 4) {
                const float m = msr[t];
#pragma unroll
                for (int j = 0; j < 8; ++j) p[j] = m * ev[j][c];
            } else if (t < 6) {
                const float m = mva[t-4][c];
#pragma unroll
                for (int j = 0; j < 8; ++j) p[j] = m * es[j];
            } else {
                const int u = t - 6;
                const float v1 = mva[u][c1], v2 = mva[u][c2i];
#pragma unroll
                for (int j = 0; j < 8; ++j) p[j] = v1*ev[j][c2i] - v2*ev[j][c1];
            }
            half8 ah, al; split8s(p, ah, al);
            mfma_tri(ah, al, B2vH[t*64 + lane], B2vL[t*64 + lane], acc, accR);
        }
#pragma unroll
        for (int r2 = 0; r2 < 4; ++r2) acc[r2] = acc[r2] + accR[r2]*RSI;
        accv[c] = acc;
    }
#pragma unroll
    for (int r2 = 0; r2 < 4; ++r2) {
        const int row = q*4 + r2;
        const float gt = C_LV / (1.f + __expf(-hsL[row*49 + 32 + n]));
#pragma unroll
        for (int c = 0; c < 3; ++c) gvL[row*49 + c*16 + n] = accv[c][r2] * gt;
    }
    LDS_FENCE();   // gvL visible to wave

    // vector epilogue
    {
        float ov[3][2] = {{0.f,0.f},{0.f,0.f},{0.f,0.f}};
#pragma unroll 4
        for (int k = 0; k < 16; ++k) {
            const float2 w = *(const float2*)(Lmv + k*8 + 2*q);
#pragma unroll
            for (int c = 0; c < 3; ++c) {
                const float gv = gvL[n*49 + c*16 + k];
                ov[c][0] = fmaf(gv, w.x, ov[c][0]);
                ov[c][1] = fmaf(gv, w.y, ov[c][1]);
            }
        }
        if (e0 + n < E) {
#pragma unroll
            for (int o2 = 0; o2 < 2; ++o2)
#pragma unroll
                for (int c = 0; c < 3; ++c)
                    m2h[(size_t)slot*40 + 16 + 3*(2*q + o2) + c] = ov[c][o2];
        }
    }
}

// =====================================================================
// CSR build
// =====================================================================
__global__ void hist_k(const int* __restrict__ ei, int* __restrict__ deg, int E) {
    const int e = blockIdx.x*256 + threadIdx.x;
    if (e < E) atomicAdd(&deg[ei[E + e]], 1);
}
__global__ void scan_k(const int* __restrict__ deg, int* __restrict__ offs,
                       int* __restrict__ pos, int N) {
    __shared__ int sm[1024];
    const int t = threadIdx.x;
    const int chunk = (N + 1023) / 1024;
    const int lo = t * chunk, hi = min(lo + chunk, N);
    int s = 0;
    for (int i = lo; i < hi; ++i) s += deg[i];
    sm[t] = s; __syncthreads();
    for (int off = 1; off < 1024; off <<= 1) {
        int v = (t >= off) ? sm[t - off] : 0;
        __syncthreads();
        sm[t] += v;
        __syncthreads();
    }
    int base = sm[t] - s;
    for (int i = lo; i < hi; ++i) { offs[i] = base; pos[i] = base; base += deg[i]; }
}
// fill_k now emits the inverse permutation rank[e] = CSR slot of edge e
__global__ void fill_k(const int* __restrict__ ei, int* __restrict__ pos,
                       int* __restrict__ rank, int E) {
    const int e = blockIdx.x*256 + threadIdx.x;
    if (e < E) { int p = atomicAdd(&pos[ei[E + e]], 1); rank[e] = p; }
}

// =====================================================================
// agg_k: m2h is already CSR-ordered -> fully sequential streaming reads
// =====================================================================
__global__ __launch_bounds__(256)
void agg_k(const float* __restrict__ m2h,
           const int* __restrict__ deg, const int* __restrict__ offs,
           float* __restrict__ agg, int N)
{
    const int n = blockIdx.x*256 + threadIdx.x;
    if (n >= N) return;
    float a[40];
#pragma unroll
    for (int u = 0; u < 40; ++u) a[u] = 0.f;
    const int cnt = deg[n];
    const float4* mp = (const float4*)(m2h + (size_t)offs[n]*40);
    for (int t = 0; t < cnt; ++t) {
#pragma unroll
        for (int u = 0; u < 10; ++u) {
            float4 v = mp[(size_t)t*10 + u];
            a[4*u] += v.x; a[4*u+1] += v.y; a[4*u+2] += v.z; a[4*u+3] += v.w;
        }
    }
    float4* o = (float4*)(agg + (size_t)n*40);
#pragma unroll
    for (int u = 0; u < 10; ++u) o[u] = make_float4(a[4*u], a[4*u+1], a[4*u+2], a[4*u+3]);
}

// =====================================================================
// node_mfma: TP(node, agg) via split-MFMA + gate + linear -> out[N,40]
// Wave = 16 nodes. No __syncthreads: per-wave LDS + wave fences.
// =====================================================================
__global__ __launch_bounds__(256)
void node_mfma(const float* __restrict__ ns, const float* __restrict__ nv,
               const float* __restrict__ agg,
               const _Float16* __restrict__ B3sh, const _Float16* __restrict__ B3sl,
               const _Float16* __restrict__ B3vh, const _Float16* __restrict__ B3vl,
               const float* __restrict__ Lus, const float* __restrict__ Luv,
               float* __restrict__ out, int N)
{
    __shared__ float ep[4][2][16*49];    // [wave][{hs,gv}][node][49]
    const int lane = threadIdx.x & 63;
    const int wv = threadIdx.x >> 6;
    const int n0 = (blockIdx.x*4 + wv) * 16;
    const int q = lane >> 4, n = lane & 15;
    const int nd = min(n0 + n, N - 1);
    const int qh = q >> 1, ql = q & 1;

    // row side = node features
    float rs_sel[8], rs4[4], rva[2][3], rvs[4][3];
#pragma unroll
    for (int t = 0; t < 8; ++t) rs_sel[t] = ns[(size_t)nd*16 + 2*t + qh];
#pragma unroll
    for (int t = 0; t < 4; ++t) rs4[t] = ns[(size_t)nd*16 + 4*t + q];
#pragma unroll
    for (int cc = 0; cc < 3; ++cc) {
        rva[0][cc] = nv[(size_t)nd*24 + 3*q + cc];
        rva[1][cc] = nv[(size_t)nd*24 + 3*(q+4) + cc];
    }
#pragma unroll
    for (int u = 0; u < 4; ++u)
#pragma unroll
        for (int cc = 0; cc < 3; ++cc) rvs[u][cc] = nv[(size_t)nd*24 + 3*(2*u+qh) + cc];
    // col side = aggregated features
    float csh[8], cv[8][3];
    {
        const float4* p = (const float4*)(agg + (size_t)nd*40 + ql*8);
#pragma unroll
        for (int t = 0; t < 2; ++t) { float4 v = p[t]; csh[4*t]=v.x; csh[4*t+1]=v.y; csh[4*t+2]=v.z; csh[4*t+3]=v.w; }
        const float4* pv = (const float4*)(agg + (size_t)nd*40 + 16);
        float tmp[24];
#pragma unroll
        for (int t = 0; t < 6; ++t) { float4 v = pv[t]; tmp[4*t]=v.x; tmp[4*t+1]=v.y; tmp[4*t+2]=v.z; tmp[4*t+3]=v.w; }
#pragma unroll
        for (int k = 0; k < 8; ++k) { cv[k][0]=tmp[3*k]; cv[k][1]=tmp[3*k+1]; cv[k][2]=tmp[3*k+2]; }
    }

    const half8* B3sH = (const half8*)B3sh; const half8* B3sL = (const half8*)B3sl;
    const half8* B3vH = (const half8*)B3vh; const half8* B3vL = (const half8*)B3vl;

    // ---- scalar GEMM: [16n x 320] @ [320 x 48] ----
    floatx4 accs[3], accsR[3];
#pragma unroll
    for (int t = 0; t < 3; ++t) { accs[t] = (floatx4){0.f,0.f,0.f,0.f}; accsR[t] = (floatx4){0.f,0.f,0.f,0.f}; }
#pragma unroll
    for (int t = 0; t < 10; ++t) {
        float p[8];
        if (t < 8) {
            const float m = rs_sel[t];
#pragma unroll
            for (int j = 0; j < 8; ++j) p[j] = m * csh[j];
        } else {
            const int u = t - 8;
            const float vx = rva[u][0], vy = rva[u][1], vz = rva[u][2];
#pragma unroll
            for (int j = 0; j < 8; ++j) p[j] = fmaf(vx, cv[j][0], fmaf(vy, cv[j][1], vz*cv[j][2]));
        }
        half8 ah, al; split8s(p, ah, al);
#pragma unroll
        for (int tn = 0; tn < 3; ++tn)
            mfma_tri(ah, al, B3sH[(tn*10 + t)*64 + lane], B3sL[(tn*10 + t)*64 + lane], accs[tn], accsR[tn]);
    }

    float* hsL = &ep[wv][0][0];
    float* gvL = &ep[wv][1][0];
#pragma unroll
    for (int t = 0; t < 3; ++t)
#pragma unroll
        for (int r2 = 0; r2 < 4; ++r2) {
            const int row = q*4 + r2;
            const float v = accs[t][r2] + accsR[t][r2]*RSI;
            if (t < 2) hsL[row*49 + t*16 + n] = v / (1.f + __expf(-v)) * C_LS;
            else       hsL[row*49 + 32 + n] = v;
        }
    LDS_FENCE();   // hsL visible to wave

    // scalar epilogue -> out[:, 0:16]
    {
        float os[4] = {0.f, 0.f, 0.f, 0.f};
#pragma unroll 4
        for (int s = 0; s < 32; ++s) {
            const float hv_ = hsL[n*49 + s];
            const float4 w = *(const float4*)(Lus + s*16 + 4*q);
            os[0] = fmaf(hv_, w.x, os[0]); os[1] = fmaf(hv_, w.y, os[1]);
            os[2] = fmaf(hv_, w.z, os[2]); os[3] = fmaf(hv_, w.w, os[3]);
        }
        if (n0 + n < N) {
#pragma unroll
            for (int u = 0; u < 4; ++u)
                out[(size_t)(n0 + n)*40 + 4*q + u] = os[u];
        }
    }

    // ---- vector GEMMs per component: [16n x 320] @ [320 x 16] ----
    floatx4 accv[3];
#pragma unroll 1
    for (int c = 0; c < 3; ++c) {
        const int c1 = (c+1)%3, c2i = (c+2)%3;
        floatx4 acc = {0.f,0.f,0.f,0.f}, accR = {0.f,0.f,0.f,0.f};
#pragma unroll
        for (int t = 0; t < 10; ++t) {
            float p[8];
            if (t < 4) {
                const float m = rs4[t];
#pragma unroll
                for (int j = 0; j < 8; ++j) p[j] = m * cv[j][c];
            } else if (t < 8) {
                const float m = rvs[t-4][c];
#pragma unroll
                for (int j = 0; j < 8; ++j) p[j] = m * csh[j];
            } else {
                const int u = t - 8;
                const float v1 = rva[u][c1], v2 = rva[u][c2i];
#pragma unroll
                for (int j = 0; j < 8; ++j) p[j] = v1*cv[j][c2i] - v2*cv[j][c1];
            }
            half8 ah, al; split8s(p, ah, al);
            mfma_tri(ah, al, B3vH[t*64 + lane], B3vL[t*64 + lane], acc, accR);
        }
#pragma unroll
        for (int r2 = 0; r2 < 4; ++r2) acc[r2] = acc[r2] + accR[r2]*RSI;
        accv[c] = acc;
    }
#pragma unroll
    for (int r2 = 0; r2 < 4; ++r2) {
        const int row = q*4 + r2;
        const float gt = C_LV / (1.f + __expf(-hsL[row*49 + 32 + n]));
#pragma unroll
        for (int c = 0; c < 3; ++c) gvL[row*49 + c*16 + n] = accv[c][r2] * gt;
    }
    LDS_FENCE();   // gvL visible to wave

    // vector epilogue -> out[:, 16:40]
    {
        float ov[3][2] = {{0.f,0.f},{0.f,0.f},{0.f,0.f}};
#pragma unroll 4
        for (int k = 0; k < 16; ++k) {
            const float2 w = *(const float2*)(Luv + k*8 + 2*q);
#pragma unroll
            for (int c = 0; c < 3; ++c) {
                const float gv = gvL[n*49 + c*16 + k];
                ov[c][0] = fmaf(gv, w.x, ov[c][0]);
                ov[c][1] = fmaf(gv, w.y, ov[c][1]);
            }
        }
        if (n0 + n < N) {
#pragma unroll
            for (int o2 = 0; o2 < 2; ++o2)
#pragma unroll
                for (int c = 0; c < 3; ++c)
                    out[(size_t)(n0 + n)*40 + 16 + 3*(2*q + o2) + c] = ov[c][o2];
        }
    }
}

// =====================================================================
extern "C" void kernel_launch(void* const* d_in, const int* in_sizes, int n_in,
                              void* d_out, int out_size, void* d_ws, size_t ws_size,
                              hipStream_t stream) {
    const float* node_s = (const float*)d_in[0];
    const float* node_v = (const float*)d_in[1];
    const float* edge_s = (const float*)d_in[3];
    const float* edge_v = (const float*)d_in[4];
    const int*   ei     = (const int*)d_in[5];
    const float* W1ss = (const float*)d_in[6];
    const float* W1sv = (const float*)d_in[7];
    const float* W1vs = (const float*)d_in[8];
    const float* W1vvs= (const float*)d_in[9];
    const float* W1vvv= (const float*)d_in[10];
    const float* W2ss = (const float*)d_in[11];
    const float* W2sv = (const float*)d_in[12];
    const float* W2vs = (const float*)d_in[13];
    const float* W2vvs= (const float*)d_in[14];
    const float* W2vvv= (const float*)d_in[15];
    const float* Lms  = (const float*)d_in[16];
    const float* Lmv  = (const float*)d_in[17];
    const float* W3ss = (const float*)d_in[18];
    const float* W3sv = (const float*)d_in[19];
    const float* W3vs = (const float*)d_in[20];
    const float* W3vvs= (const float*)d_in[21];
    const float* W3vvv= (const float*)d_in[22];
    const float* Lus  = (const float*)d_in[23];
    const float* Luv  = (const float*)d_in[24];

    float* out = (float*)d_out;
    const int N = in_sizes[0] / 16;
    const int E = in_sizes[5] / 2;

    // ws layout: fp16 B-frags, fp32 messages, fp32 agg, CSR ints
    _Float16* B1sh = (_Float16*)d_ws;             // 5120
    _Float16* B1sl = B1sh + 5120;
    _Float16* B1vh = B1sl + 5120;
    _Float16* B1vl = B1vh + 5120;
    _Float16* B2sh = B1vl + 5120;                 // 9216
    _Float16* B2sl = B2sh + 9216;
    _Float16* B2vh = B2sl + 9216;                 // 4096
    _Float16* B2vl = B2vh + 4096;
    _Float16* B3sh = B2vl + 4096;                 // 15360
    _Float16* B3sl = B3sh + 15360;
    _Float16* B3vh = B3sl + 15360;                // 5120
    _Float16* B3vl = B3vh + 5120;                 // ends at 88064 halves = 176128 B
    float* m2h = (float*)((char*)d_ws + 176128);  // [E][40] fp32 (CSR-ordered)
    float* agg = m2h + (size_t)40*E;              // [N][40] fp32
    int* deg   = (int*)(agg + (size_t)40*N);      // N
    int* offs  = deg + N;
    int* pos   = offs + N;
    int* rank  = pos + N;                         // E (inverse CSR permutation)

    hipMemsetAsync(deg, 0, (size_t)N * sizeof(int), stream);

    prep_w<<<88, 256, 0, stream>>>(W1ss, W1sv, W1vs, W1vvs, W1vvv,
                                   W2ss, W2sv, W2vs, W2vvs, W2vvv,
                                   W3ss, W3sv, W3vs, W3vvs, W3vvv,
                                   B1sh, B1sl, B1vh, B1vl, B2sh, B2sl, B2vh, B2vl,
                                   B3sh, B3sl, B3vh, B3vl);

    hist_k<<<(E + 255)/256, 256, 0, stream>>>(ei, deg, E);
    scan_k<<<1, 1024, 0, stream>>>(deg, offs, pos, N);
    fill_k<<<(E + 255)/256, 256, 0, stream>>>(ei, pos, rank, E);

    const int tpblocks = (E + 63) / 64;   // 4 waves/block, 16 edges/wave
    edge_fused<<<tpblocks, 256, 0, stream>>>(
        node_s, node_v, edge_s, edge_v, ei, rank,
        B1sh, B1sl, B1vh, B1vl, B2sh, B2sl, B2vh, B2vl,
        Lms, Lmv, m2h, E);

    agg_k<<<(N + 255)/256, 256, 0, stream>>>(m2h, deg, offs, agg, N);

    const int ndblocks = ((N + 15)/16 + 3) / 4;   // 4 waves/block, 16 nodes/wave
    node_mfma<<<ndblocks, 256, 0, stream>>>(
        node_s, node_v, agg, B3sh, B3sl, B3vh, B3vl, Lus, Luv, out, N);
}

// Round 8
// 640.714 us; speedup vs baseline: 1.0711x; 1.0048x over previous
//
#include <hip/hip_runtime.h>
#include <math.h>

typedef _Float16 half8 __attribute__((ext_vector_type(8)));
typedef float floatx4 __attribute__((ext_vector_type(4)));

constexpr float C_SS16 = 0.04419417382415922f;  // i2/16
constexpr float C_UNI  = 0.05103103630798288f;  // i3/sqrt(128)
constexpr float C2_SS  = 0.0625f;               // i2/sqrt(128)
constexpr float C2_VS  = 0.07216878364870323f;  // i3/8
constexpr float C_LS   = 0.17677669529663687f;  // 1/sqrt(32)
constexpr float C_LV   = 0.25f;                 // 1/sqrt(16)
constexpr float RS     = 2048.0f;               // residual scale (keeps lo-parts normal in fp16)
constexpr float RSI    = 1.0f / 2048.0f;

// split fp32 -> fp16 hi + SCALED fp16 residual (residual*2048 stays normal-range)
__device__ __forceinline__ void split8s(const float* p, half8& ah, half8& alS) {
#pragma unroll
    for (int j = 0; j < 8; ++j) {
        _Float16 h = (_Float16)p[j];
        ah[j] = h;
        alS[j] = (_Float16)((p[j] - (float)h) * RS);
    }
}
// 3-term split MFMA with separate scaled-residual accumulator
__device__ __forceinline__ void mfma_tri(half8 ah, half8 alS, half8 bh, half8 blS,
                                         floatx4& acc, floatx4& accR) {
    acc  = __builtin_amdgcn_mfma_f32_16x16x32_f16(ah,  bh,  acc,  0, 0, 0);
    accR = __builtin_amdgcn_mfma_f32_16x16x32_f16(alS, bh,  accR, 0, 0, 0);
    accR = __builtin_amdgcn_mfma_f32_16x16x32_f16(ah,  blS, accR, 0, 0, 0);
}

// =====================================================================
// Weight prep: fp32 -> (fp16 hi, fp16 lo*2048) B-fragments, norms folded.
// Grid-stride (88 blocks): per-element math is a pure function of idx —
// bit-identical to the single-block R0 version, just parallel.
// =====================================================================
__global__ void prep_w(const float* __restrict__ W1ss, const float* __restrict__ W1sv,
                       const float* __restrict__ W1vs, const float* __restrict__ W1vvs,
                       const float* __restrict__ W1vvv,
                       const float* __restrict__ W2ss, const float* __restrict__ W2sv,
                       const float* __restrict__ W2vs, const float* __restrict__ W2vvs,
                       const float* __restrict__ W2vvv,
                       const float* __restrict__ W3ss, const float* __restrict__ W3sv,
                       const float* __restrict__ W3vs, const float* __restrict__ W3vvs,
                       const float* __restrict__ W3vvv,
                       _Float16* B1sh, _Float16* B1sl, _Float16* B1vh, _Float16* B1vl,
                       _Float16* B2sh, _Float16* B2sl, _Float16* B2vh, _Float16* B2vl,
                       _Float16* B3sh, _Float16* B3sl, _Float16* B3vh, _Float16* B3vl)
{
    const int t0 = blockIdx.x*256 + threadIdx.x;
    const int gs = gridDim.x*256;
    // B1s: Tk=10, K=320 (256 ss + 64 vvs), 16 cols
    for (int idx = t0; idx < 10*512; idx += gs) {
        int t_k = idx >> 9, lane = (idx >> 3) & 63, j = idx & 7;
        int q = lane >> 4, n = lane & 15;
        int k = t_k*32 + q*8 + j;
        float v;
        if (k < 256) { int i = k>>4, jj = k&15; v = W1ss[(i*16+jj)*16+n] * C_SS16; }
        else { int kk = k-256; int i = kk>>3, jj = kk&7; v = W1vvs[(i*8+jj)*16+n] * C_UNI; }
        _Float16 h = (_Float16)v;
        B1sh[idx] = h; B1sl[idx] = (_Float16)((v - (float)h) * RS);
    }
    // B1v: Tk=10, K=320 (128 sv + 128 vs + 64 vvv), 8 cols (8..15 zero)
    for (int idx = t0; idx < 10*512; idx += gs) {
        int t_k = idx >> 9, lane = (idx >> 3) & 63, j = idx & 7;
        int q = lane >> 4, n = lane & 15;
        int k = t_k*32 + q*8 + j;
        float v = 0.f;
        if (n < 8) {
            if (k < 128) { int i = k>>3, jj = k&7; v = W1sv[(i*8+jj)*8+n] * C_UNI; }
            else if (k < 256) { int kk = k-128; int i = kk>>4, jj = kk&15; v = W1vs[(i*16+jj)*8+n] * C_UNI; }
            else { int kk = k-256; int i = kk>>3, jj = kk&7; v = W1vvv[(i*8+jj)*8+n] * C_UNI; }
        }
        _Float16 h = (_Float16)v;
        B1vh[idx] = h; B1vl[idx] = (_Float16)((v - (float)h) * RS);
    }
    // B2s: Tn=3, Tk=6, K=192 (128 ss + 64 vvs), 48 cols
    for (int idx = t0; idx < 3*6*512; idx += gs) {
        int tn = idx / 3072, t_k = (idx % 3072) >> 9, lane = (idx >> 3) & 63, j = idx & 7;
        int q = lane >> 4, n = lane & 15, col = tn*16 + n;
        int k = t_k*32 + q*8 + j;
        float v;
        if (k < 128) { int i = k>>3, jj = k&7; v = W2ss[(i*8+jj)*48+col] * C2_SS; }
        else { int kk = k-128; int i = kk>>3, jj = kk&7; v = W2vvs[(i*8+jj)*48+col] * C_UNI; }
        _Float16 h = (_Float16)v;
        B2sh[idx] = h; B2sl[idx] = (_Float16)((v - (float)h) * RS);
    }
    // B2v: Tk=8, K=256 (128 sv + 64 vs + 64 vvv), 16 cols
    for (int idx = t0; idx < 8*512; idx += gs) {
        int t_k = idx >> 9, lane = (idx >> 3) & 63, j = idx & 7;
        int q = lane >> 4, n = lane & 15;
        int k = t_k*32 + q*8 + j;
        float v;
        if (k < 128) { int i = k>>3, jj = k&7; v = W2sv[(i*8+jj)*16+n] * C_UNI; }
        else if (k < 192) { int kk = k-128; int i = kk>>3, jj = kk&7; v = W2vs[(i*8+jj)*16+n] * C2_VS; }
        else { int kk = k-192; int i = kk>>3, jj = kk&7; v = W2vvv[(i*8+jj)*16+n] * C_UNI; }
        _Float16 h = (_Float16)v;
        B2vh[idx] = h; B2vl[idx] = (_Float16)((v - (float)h) * RS);
    }
    // B3s: Tn=3, Tk=10, K=320 (256 ss + 64 vvs), 48 cols
    for (int idx = t0; idx < 3*10*512; idx += gs) {
        int tn = idx / 5120, rem = idx % 5120;
        int t_k = rem >> 9, lane = (rem >> 3) & 63, j = rem & 7;
        int q = lane >> 4, n = lane & 15, col = tn*16 + n;
        int k = t_k*32 + q*8 + j;
        float v;
        if (k < 256) { int i = k>>4, jj = k&15; v = W3ss[(i*16+jj)*48+col] * C_SS16; }
        else { int kk = k-256; int i = kk>>3, jj = kk&7; v = W3vvs[(i*8+jj)*48+col] * C_UNI; }
        _Float16 h = (_Float16)v;
        B3sh[idx] = h; B3sl[idx] = (_Float16)((v - (float)h) * RS);
    }
    // B3v: Tk=10, K=320 (128 sv + 128 vs + 64 vvv), 16 cols
    for (int idx = t0; idx < 10*512; idx += gs) {
        int t_k = idx >> 9, lane = (idx >> 3) & 63, j = idx & 7;
        int q = lane >> 4, n = lane & 15;
        int k = t_k*32 + q*8 + j;
        float v;
        if (k < 128) { int i = k>>3, jj = k&7; v = W3sv[(i*8+jj)*16+n] * C_UNI; }
        else if (k < 256) { int kk = k-128; int i = kk>>4, jj = kk&15; v = W3vs[(i*16+jj)*16+n] * C_UNI; }
        else { int kk = k-256; int i = kk>>3, jj = kk&7; v = W3vvv[(i*8+jj)*16+n] * C_UNI; }
        _Float16 h = (_Float16)v;
        B3vh[idx] = h; B3vl[idx] = (_Float16)((v - (float)h) * RS);
    }
}

// =====================================================================
// Fused edge kernel: stage1 MFMA -> LDS transpose -> stage2 MFMA -> gate
// -> linear -> m2h[E][40] fp32 messages. Wave = 16 edges.
// EXACT R0 structure (harness-verified 686.8us / absmax 0.164).
// =====================================================================
__global__ __launch_bounds__(256)
void edge_fused(const float* __restrict__ ns, const float* __restrict__ nv,
                const float* __restrict__ edge_s, const float* __restrict__ edge_v,
                const int* __restrict__ ei,
                const _Float16* __restrict__ B1sh, const _Float16* __restrict__ B1sl,
                const _Float16* __restrict__ B1vh, const _Float16* __restrict__ B1vl,
                const _Float16* __restrict__ B2sh, const _Float16* __restrict__ B2sl,
                const _Float16* __restrict__ B2vh, const _Float16* __restrict__ B2vl,
                const float* __restrict__ Lms, const float* __restrict__ Lmv,
                float* __restrict__ m2h, int E)
{
    __shared__ float mT[4][16*41];       // [wave][edge][41] m transpose
    __shared__ float ep[4][2][16*49];    // [wave][{hs,gv}][edge][49]
    const int lane = threadIdx.x & 63;
    const int wv = threadIdx.x >> 6;
    const int e0 = (blockIdx.x*4 + wv) * 16;
    const int q = lane >> 4, n = lane & 15;
    const int e = min(e0 + n, E - 1);
    const int qh = q >> 1, ql = q & 1;
    const int r = ei[e], c2 = ei[E + e];

    // ---------------- stage 1 feature slices ----------------
    float rs_sel[8], rs4[4], rva[2][3], rvs[4][3], csh[8], cv[8][3];
#pragma unroll
    for (int t = 0; t < 8; ++t) rs_sel[t] = ns[(size_t)r*16 + 2*t + qh];
#pragma unroll
    for (int t = 0; t < 4; ++t) rs4[t] = ns[(size_t)r*16 + 4*t + q];
#pragma unroll
    for (int cc = 0; cc < 3; ++cc) {
        rva[0][cc] = nv[(size_t)r*24 + 3*q + cc];
        rva[1][cc] = nv[(size_t)r*24 + 3*(q+4) + cc];
    }
#pragma unroll
    for (int u = 0; u < 4; ++u)
#pragma unroll
        for (int cc = 0; cc < 3; ++cc) rvs[u][cc] = nv[(size_t)r*24 + 3*(2*u+qh) + cc];
    {
        const float4* p = (const float4*)(ns + (size_t)c2*16 + ql*8);
#pragma unroll
        for (int t = 0; t < 2; ++t) { float4 v = p[t]; csh[4*t]=v.x; csh[4*t+1]=v.y; csh[4*t+2]=v.z; csh[4*t+3]=v.w; }
        const float4* pv = (const float4*)(nv + (size_t)c2*24);
        float tmp[24];
#pragma unroll
        for (int t = 0; t < 6; ++t) { float4 v = pv[t]; tmp[4*t]=v.x; tmp[4*t+1]=v.y; tmp[4*t+2]=v.z; tmp[4*t+3]=v.w; }
#pragma unroll
        for (int k = 0; k < 8; ++k) { cv[k][0]=tmp[3*k]; cv[k][1]=tmp[3*k+1]; cv[k][2]=tmp[3*k+2]; }
    }

    const half8* B1sH = (const half8*)B1sh; const half8* B1sL = (const half8*)B1sl;
    const half8* B1vH = (const half8*)B1vh; const half8* B1vL = (const half8*)B1vl;

    // ---- stage1 scalar GEMM: [16e x 320] @ [320 x 16] ----
    {
        floatx4 acc = {0.f,0.f,0.f,0.f}, accR = {0.f,0.f,0.f,0.f};
#pragma unroll
        for (int t = 0; t < 10; ++t) {
            float p[8];
            if (t < 8) {
                const float m = rs_sel[t];
#pragma unroll
                for (int j = 0; j < 8; ++j) p[j] = m * csh[j];
            } else {
                const int u = t - 8;
                const float vx = rva[u][0], vy = rva[u][1], vz = rva[u][2];
#pragma unroll
                for (int j = 0; j < 8; ++j) p[j] = fmaf(vx, cv[j][0], fmaf(vy, cv[j][1], vz*cv[j][2]));
            }
            half8 ah, al; split8s(p, ah, al);
            mfma_tri(ah, al, B1sH[t*64 + lane], B1sL[t*64 + lane], acc, accR);
        }
#pragma unroll
        for (int r2 = 0; r2 < 4; ++r2)
            mT[wv][(q*4 + r2)*41 + n] = acc[r2] + accR[r2]*RSI;
    }
    // ---- stage1 vector GEMMs per component ----
#pragma unroll 1
    for (int c = 0; c < 3; ++c) {
        const int c1 = (c+1)%3, c2i = (c+2)%3;
        floatx4 acc = {0.f,0.f,0.f,0.f}, accR = {0.f,0.f,0.f,0.f};
#pragma unroll
        for (int t = 0; t < 10; ++t) {
            float p[8];
            if (t < 4) {
                const float m = rs4[t];
#pragma unroll
                for (int j = 0; j < 8; ++j) p[j] = m * cv[j][c];
            } else if (t < 8) {
                const float m = rvs[t-4][c];
#pragma unroll
                for (int j = 0; j < 8; ++j) p[j] = m * csh[j];
            } else {
                const int u = t - 8;
                const float v1 = rva[u][c1], v2 = rva[u][c2i];
#pragma unroll
                for (int j = 0; j < 8; ++j) p[j] = v1*cv[j][c2i] - v2*cv[j][c1];
            }
            half8 ah, al; split8s(p, ah, al);
            mfma_tri(ah, al, B1vH[t*64 + lane], B1vL[t*64 + lane], acc, accR);
        }
        if (n < 8) {
#pragma unroll
            for (int r2 = 0; r2 < 4; ++r2)
                mT[wv][(q*4 + r2)*41 + 16 + 3*n + c] = acc[r2] + accR[r2]*RSI;
        }
    }
    __syncthreads();

    // ---------------- stage 2 inputs ----------------
    float msr[4], mva[2][3], es[8], ev[8][3];
#pragma unroll
    for (int t = 0; t < 4; ++t) msr[t] = mT[wv][n*41 + 4*t + q];
#pragma unroll
    for (int u = 0; u < 2; ++u)
#pragma unroll
        for (int cc = 0; cc < 3; ++cc) mva[u][cc] = mT[wv][n*41 + 16 + 3*(4*u+q) + cc];
    {
        const float4* p = (const float4*)(edge_s + (size_t)e*8);
#pragma unroll
        for (int t = 0; t < 2; ++t) { float4 v = p[t]; es[4*t]=v.x; es[4*t+1]=v.y; es[4*t+2]=v.z; es[4*t+3]=v.w; }
        const float4* pv = (const float4*)(edge_v + (size_t)e*24);
        float tmp[24];
#pragma unroll
        for (int t = 0; t < 6; ++t) { float4 v = pv[t]; tmp[4*t]=v.x; tmp[4*t+1]=v.y; tmp[4*t+2]=v.z; tmp[4*t+3]=v.w; }
#pragma unroll
        for (int k = 0; k < 8; ++k) { ev[k][0]=tmp[3*k]; ev[k][1]=tmp[3*k+1]; ev[k][2]=tmp[3*k+2]; }
    }

    const half8* B2sH = (const half8*)B2sh; const half8* B2sL = (const half8*)B2sl;
    const half8* B2vH = (const half8*)B2vh; const half8* B2vL = (const half8*)B2vl;

    // ---- stage2 scalar GEMM: [16e x 192] @ [192 x 48] ----
    floatx4 accs[3], accsR[3];
#pragma unroll
    for (int t = 0; t < 3; ++t) { accs[t] = (floatx4){0.f,0.f,0.f,0.f}; accsR[t] = (floatx4){0.f,0.f,0.f,0.f}; }
#pragma unroll
    for (int t = 0; t < 6; ++t) {
        float p[8];
        if (t < 4) {
            const float m = msr[t];
#pragma unroll
            for (int j = 0; j < 8; ++j) p[j] = m * es[j];
        } else {
            const int u = t - 4;
            const float vx = mva[u][0], vy = mva[u][1], vz = mva[u][2];
#pragma unroll
            for (int j = 0; j < 8; ++j) p[j] = fmaf(vx, ev[j][0], fmaf(vy, ev[j][1], vz*ev[j][2]));
        }
        half8 ah, al; split8s(p, ah, al);
#pragma unroll
        for (int tn = 0; tn < 3; ++tn)
            mfma_tri(ah, al, B2sH[(tn*6 + t)*64 + lane], B2sL[(tn*6 + t)*64 + lane], accs[tn], accsR[tn]);
    }

    float* hsL = &ep[wv][0][0];
    float* gvL = &ep[wv][1][0];
#pragma unroll
    for (int t = 0; t < 3; ++t)
#pragma unroll
        for (int r2 = 0; r2 < 4; ++r2) {
            const int row = q*4 + r2;
            const float v = accs[t][r2] + accsR[t][r2]*RSI;
            if (t < 2) hsL[row*49 + t*16 + n] = v / (1.f + __expf(-v)) * C_LS;
            else       hsL[row*49 + 32 + n] = v;
        }
    __syncthreads();

    // scalar epilogue
    {
        float os[4] = {0.f, 0.f, 0.f, 0.f};
#pragma unroll 4
        for (int s = 0; s < 32; ++s) {
            const float hv_ = hsL[n*49 + s];
            const float4 w = *(const float4*)(Lms + s*16 + 4*q);
            os[0] = fmaf(hv_, w.x, os[0]); os[1] = fmaf(hv_, w.y, os[1]);
            os[2] = fmaf(hv_, w.z, os[2]); os[3] = fmaf(hv_, w.w, os[3]);
        }
        if (e0 + n < E) {
#pragma unroll
            for (int u = 0; u < 4; ++u)
                m2h[(size_t)(e0 + n)*40 + 4*q + u] = os[u];
        }
    }

    // ---- stage2 vector GEMMs ----
    floatx4 accv[3];
#pragma unroll 1
    for (int c = 0; c < 3; ++c) {
        const int c1 = (c+1)%3, c2i = (c+2)%3;
        floatx4 acc = {0.f,0.f,0.f,0.f}, accR = {0.f,0.f,0.f,0.f};
#pragma unroll
        for (int t = 0; t < 8; ++t) {
            float p[8];
            if (t < 4) {
                const float m = msr[t];
#pragma unroll
                for (int j = 0; j < 8; ++j) p[j] = m * ev[j][c];
            } else if (t < 6) {
                const float m = mva[t-4][c];
#pragma unroll
                for (int j = 0; j < 8; ++j) p[j] = m * es[j];
            } else {
                const int u = t - 6;
                const float v1 = mva[u][c1], v2 = mva[u][c2i];
#pragma unroll
                for (int j = 0; j < 8; ++j) p[j] = v1*ev[j][c2i] - v2*ev[j][c1];
            }
            half8 ah, al; split8s(p, ah, al);
            mfma_tri(ah, al, B2vH[t*64 + lane], B2vL[t*64 + lane], acc, accR);
        }
#pragma unroll
        for (int r2 = 0; r2 < 4; ++r2) acc[r2] = acc[r2] + accR[r2]*RSI;
        accv[c] = acc;
    }
#pragma unroll
    for (int r2 = 0; r2 < 4; ++r2) {
        const int row = q*4 + r2;
        const float gt = C_LV / (1.f + __expf(-hsL[row*49 + 32 + n]));
#pragma unroll
        for (int c = 0; c < 3; ++c) gvL[row*49 + c*16 + n] = accv[c][r2] * gt;
    }
    __syncthreads();

    // vector epilogue
    {
        float ov[3][2] = {{0.f,0.f},{0.f,0.f},{0.f,0.f}};
#pragma unroll 4
        for (int k = 0; k < 16; ++k) {
            const float2 w = *(const float2*)(Lmv + k*8 + 2*q);
#pragma unroll
            for (int c = 0; c < 3; ++c) {
                const float gv = gvL[n*49 + c*16 + k];
                ov[c][0] = fmaf(gv, w.x, ov[c][0]);
                ov[c][1] = fmaf(gv, w.y, ov[c][1]);
            }
        }
        if (e0 + n < E) {
#pragma unroll
            for (int o2 = 0; o2 < 2; ++o2)
#pragma unroll
                for (int c = 0; c < 3; ++c)
                    m2h[(size_t)(e0 + n)*40 + 16 + 3*(2*q + o2) + c] = ov[c][o2];
        }
    }
}

// =====================================================================
// CSR build
// =====================================================================
__global__ void hist_k(const int* __restrict__ ei, int* __restrict__ deg, int E) {
    const int e = blockIdx.x*256 + threadIdx.x;
    if (e < E) atomicAdd(&deg[ei[E + e]], 1);
}
__global__ void scan_k(const int* __restrict__ deg, int* __restrict__ offs,
                       int* __restrict__ pos, int N) {
    __shared__ int sm[1024];
    const int t = threadIdx.x;
    const int chunk = (N + 1023) / 1024;
    const int lo = t * chunk, hi = min(lo + chunk, N);
    int s = 0;
    for (int i = lo; i < hi; ++i) s += deg[i];
    sm[t] = s; __syncthreads();
    for (int off = 1; off < 1024; off <<= 1) {
        int v = (t >= off) ? sm[t - off] : 0;
        __syncthreads();
        sm[t] += v;
        __syncthreads();
    }
    int base = sm[t] - s;
    for (int i = lo; i < hi; ++i) { offs[i] = base; pos[i] = base; base += deg[i]; }
}
__global__ void fill_k(const int* __restrict__ ei, int* __restrict__ pos,
                       int* __restrict__ order, int E) {
    const int e = blockIdx.x*256 + threadIdx.x;
    if (e < E) { int p = atomicAdd(&pos[ei[E + e]], 1); order[p] = e; }
}

// =====================================================================
// agg_k: CSR gather-aggregate fp32 messages -> agg[N][40]  (R0-exact)
// =====================================================================
__global__ __launch_bounds__(256)
void agg_k(const float* __restrict__ m2h,
           const int* __restrict__ deg, const int* __restrict__ offs,
           const int* __restrict__ order,
           float* __restrict__ agg, int N)
{
    const int n = blockIdx.x*256 + threadIdx.x;
    if (n >= N) return;
    float a[40];
#pragma unroll
    for (int u = 0; u < 40; ++u) a[u] = 0.f;
    const int cnt = deg[n], base = offs[n];
    for (int t = 0; t < cnt; ++t) {
        const int id = order[base + t];
        const float4* mp = (const float4*)(m2h + (size_t)id*40);
#pragma unroll
        for (int u = 0; u < 10; ++u) {
            float4 v = mp[u];
            a[4*u] += v.x; a[4*u+1] += v.y; a[4*u+2] += v.z; a[4*u+3] += v.w;
        }
    }
    float4* o = (float4*)(agg + (size_t)n*40);
#pragma unroll
    for (int u = 0; u < 10; ++u) o[u] = make_float4(a[4*u], a[4*u+1], a[4*u+2], a[4*u+3]);
}

// =====================================================================
// node_mfma: TP(node, agg) via split-MFMA + gate + linear -> out[N,40]
// EXACT R0 structure.
// =====================================================================
__global__ __launch_bounds__(256)
void node_mfma(const float* __restrict__ ns, const float* __restrict__ nv,
               const float* __restrict__ agg,
               const _Float16* __restrict__ B3sh, const _Float16* __restrict__ B3sl,
               const _Float16* __restrict__ B3vh, const _Float16* __restrict__ B3vl,
               const float* __restrict__ Lus, const float* __restrict__ Luv,
               float* __restrict__ out, int N)
{
    __shared__ float ep[4][2][16*49];    // [wave][{hs,gv}][node][49]
    const int lane = threadIdx.x & 63;
    const int wv = threadIdx.x >> 6;
    const int n0 = (blockIdx.x*4 + wv) * 16;
    const int q = lane >> 4, n = lane & 15;
    const int nd = min(n0 + n, N - 1);
    const int qh = q >> 1, ql = q & 1;

    // row side = node features
    float rs_sel[8], rs4[4], rva[2][3], rvs[4][3];
#pragma unroll
    for (int t = 0; t < 8; ++t) rs_sel[t] = ns[(size_t)nd*16 + 2*t + qh];
#pragma unroll
    for (int t = 0; t < 4; ++t) rs4[t] = ns[(size_t)nd*16 + 4*t + q];
#pragma unroll
    for (int cc = 0; cc < 3; ++cc) {
        rva[0][cc] = nv[(size_t)nd*24 + 3*q + cc];
        rva[1][cc] = nv[(size_t)nd*24 + 3*(q+4) + cc];
    }
#pragma unroll
    for (int u = 0; u < 4; ++u)
#pragma unroll
        for (int cc = 0; cc < 3; ++cc) rvs[u][cc] = nv[(size_t)nd*24 + 3*(2*u+qh) + cc];
    // col side = aggregated features
    float csh[8], cv[8][3];
    {
        const float4* p = (const float4*)(agg + (size_t)nd*40 + ql*8);
#pragma unroll
        for (int t = 0; t < 2; ++t) { float4 v = p[t]; csh[4*t]=v.x; csh[4*t+1]=v.y; csh[4*t+2]=v.z; csh[4*t+3]=v.w; }
        const float4* pv = (const float4*)(agg + (size_t)nd*40 + 16);
        float tmp[24];
#pragma unroll
        for (int t = 0; t < 6; ++t) { float4 v = pv[t]; tmp[4*t]=v.x; tmp[4*t+1]=v.y; tmp[4*t+2]=v.z; tmp[4*t+3]=v.w; }
#pragma unroll
        for (int k = 0; k < 8; ++k) { cv[k][0]=tmp[3*k]; cv[k][1]=tmp[3*k+1]; cv[k][2]=tmp[3*k+2]; }
    }

    const half8* B3sH = (const half8*)B3sh; const half8* B3sL = (const half8*)B3sl;
    const half8* B3vH = (const half8*)B3vh; const half8* B3vL = (const half8*)B3vl;

    // ---- scalar GEMM: [16n x 320] @ [320 x 48] ----
    floatx4 accs[3], accsR[3];
#pragma unroll
    for (int t = 0; t < 3; ++t) { accs[t] = (floatx4){0.f,0.f,0.f,0.f}; accsR[t] = (floatx4){0.f,0.f,0.f,0.f}; }
#pragma unroll
    for (int t = 0; t < 10; ++t) {
        float p[8];
        if (t < 8) {
            const float m = rs_sel[t];
#pragma unroll
            for (int j = 0; j < 8; ++j) p[j] = m * csh[j];
        } else {
            const int u = t - 8;
            const float vx = rva[u][0], vy = rva[u][1], vz = rva[u][2];
#pragma unroll
            for (int j = 0; j < 8; ++j) p[j] = fmaf(vx, cv[j][0], fmaf(vy, cv[j][1], vz*cv[j][2]));
        }
        half8 ah, al; split8s(p, ah, al);
#pragma unroll
        for (int tn = 0; tn < 3; ++tn)
            mfma_tri(ah, al, B3sH[(tn*10 + t)*64 + lane], B3sL[(tn*10 + t)*64 + lane], accs[tn], accsR[tn]);
    }

    float* hsL = &ep[wv][0][0];
    float* gvL = &ep[wv][1][0];
#pragma unroll
    for (int t = 0; t < 3; ++t)
#pragma unroll
        for (int r2 = 0; r2 < 4; ++r2) {
            const int row = q*4 + r2;
            const float v = accs[t][r2] + accsR[t][r2]*RSI;
            if (t < 2) hsL[row*49 + t*16 + n] = v / (1.f + __expf(-v)) * C_LS;
            else       hsL[row*49 + 32 + n] = v;
        }
    __syncthreads();

    // scalar epilogue -> out[:, 0:16]
    {
        float os[4] = {0.f, 0.f, 0.f, 0.f};
#pragma unroll 4
        for (int s = 0; s < 32; ++s) {
            const float hv_ = hsL[n*49 + s];
            const float4 w = *(const float4*)(Lus + s*16 + 4*q);
            os[0] = fmaf(hv_, w.x, os[0]); os[1] = fmaf(hv_, w.y, os[1]);
            os[2] = fmaf(hv_, w.z, os[2]); os[3] = fmaf(hv_, w.w, os[3]);
        }
        if (n0 + n < N) {
#pragma unroll
            for (int u = 0; u < 4; ++u)
                out[(size_t)(n0 + n)*40 + 4*q + u] = os[u];
        }
    }

    // ---- vector GEMMs per component: [16n x 320] @ [320 x 16] ----
    floatx4 accv[3];
#pragma unroll 1
    for (int c = 0; c < 3; ++c) {
        const int c1 = (c+1)%3, c2i = (c+2)%3;
        floatx4 acc = {0.f,0.f,0.f,0.f}, accR = {0.f,0.f,0.f,0.f};
#pragma unroll
        for (int t = 0; t < 10; ++t) {
            float p[8];
            if (t < 4) {
                const float m = rs4[t];
#pragma unroll
                for (int j = 0; j < 8; ++j) p[j] = m * cv[j][c];
            } else if (t < 8) {
                const float m = rvs[t-4][c];
#pragma unroll
                for (int j = 0; j < 8; ++j) p[j] = m * csh[j];
            } else {
                const int u = t - 8;
                const float v1 = rva[u][c1], v2 = rva[u][c2i];
#pragma unroll
                for (int j = 0; j < 8; ++j) p[j] = v1*cv[j][c2i] - v2*cv[j][c1];
            }
            half8 ah, al; split8s(p, ah, al);
            mfma_tri(ah, al, B3vH[t*64 + lane], B3vL[t*64 + lane], acc, accR);
        }
#pragma unroll
        for (int r2 = 0; r2 < 4; ++r2) acc[r2] = acc[r2] + accR[r2]*RSI;
        accv[c] = acc;
    }
#pragma unroll
    for (int r2 = 0; r2 < 4; ++r2) {
        const int row = q*4 + r2;
        const float gt = C_LV / (1.f + __expf(-hsL[row*49 + 32 + n]));
#pragma unroll
        for (int c = 0; c < 3; ++c) gvL[row*49 + c*16 + n] = accv[c][r2] * gt;
    }
    __syncthreads();

    // vector epilogue -> out[:, 16:40]
    {
        float ov[3][2] = {{0.f,0.f},{0.f,0.f},{0.f,0.f}};
#pragma unroll 4
        for (int k = 0; k < 16; ++k) {
            const float2 w = *(const float2*)(Luv + k*8 + 2*q);
#pragma unroll
            for (int c = 0; c < 3; ++c) {
                const float gv = gvL[n*49 + c*16 + k];
                ov[c][0] = fmaf(gv, w.x, ov[c][0]);
                ov[c][1] = fmaf(gv, w.y, ov[c][1]);
            }
        }
        if (n0 + n < N) {
#pragma unroll
            for (int o2 = 0; o2 < 2; ++o2)
#pragma unroll
                for (int c = 0; c < 3; ++c)
                    out[(size_t)(n0 + n)*40 + 16 + 3*(2*q + o2) + c] = ov[c][o2];
        }
    }
}

// =====================================================================
extern "C" void kernel_launch(void* const* d_in, const int* in_sizes, int n_in,
                              void* d_out, int out_size, void* d_ws, size_t ws_size,
                              hipStream_t stream) {
    const float* node_s = (const float*)d_in[0];
    const float* node_v = (const float*)d_in[1];
    const float* edge_s = (const float*)d_in[3];
    const float* edge_v = (const float*)d_in[4];
    const int*   ei     = (const int*)d_in[5];
    const float* W1ss = (const float*)d_in[6];
    const float* W1sv = (const float*)d_in[7];
    const float* W1vs = (const float*)d_in[8];
    const float* W1vvs= (const float*)d_in[9];
    const float* W1vvv= (const float*)d_in[10];
    const float* W2ss = (const float*)d_in[11];
    const float* W2sv = (const float*)d_in[12];
    const float* W2vs = (const float*)d_in[13];
    const float* W2vvs= (const float*)d_in[14];
    const float* W2vvv= (const float*)d_in[15];
    const float* Lms  = (const float*)d_in[16];
    const float* Lmv  = (const float*)d_in[17];
    const float* W3ss = (const float*)d_in[18];
    const float* W3sv = (const float*)d_in[19];
    const float* W3vs = (const float*)d_in[20];
    const float* W3vvs= (const float*)d_in[21];
    const float* W3vvv= (const float*)d_in[22];
    const float* Lus  = (const float*)d_in[23];
    const float* Luv  = (const float*)d_in[24];

    float* out = (float*)d_out;
    const int N = in_sizes[0] / 16;
    const int E = in_sizes[5] / 2;

    // ws layout: fp16 B-frags, fp32 messages, fp32 agg, CSR ints
    _Float16* B1sh = (_Float16*)d_ws;             // 5120
    _Float16* B1sl = B1sh + 5120;
    _Float16* B1vh = B1sl + 5120;
    _Float16* B1vl = B1vh + 5120;
    _Float16* B2sh = B1vl + 5120;                 // 9216
    _Float16* B2sl = B2sh + 9216;
    _Float16* B2vh = B2sl + 9216;                 // 4096
    _Float16* B2vl = B2vh + 4096;
    _Float16* B3sh = B2vl + 4096;                 // 15360
    _Float16* B3sl = B3sh + 15360;
    _Float16* B3vh = B3sl + 15360;                // 5120
    _Float16* B3vl = B3vh + 5120;                 // ends at 88064 halves = 176128 B
    float* m2h = (float*)((char*)d_ws + 176128);  // [E][40] fp32
    float* agg = m2h + (size_t)40*E;              // [N][40] fp32
    int* deg   = (int*)(agg + (size_t)40*N);      // N
    int* offs  = deg + N;
    int* pos   = offs + N;
    int* order = pos + N;                         // E

    hipMemsetAsync(deg, 0, (size_t)N * sizeof(int), stream);

    prep_w<<<88, 256, 0, stream>>>(W1ss, W1sv, W1vs, W1vvs, W1vvv,
                                   W2ss, W2sv, W2vs, W2vvs, W2vvv,
                                   W3ss, W3sv, W3vs, W3vvs, W3vvv,
                                   B1sh, B1sl, B1vh, B1vl, B2sh, B2sl, B2vh, B2vl,
                                   B3sh, B3sl, B3vh, B3vl);

    hist_k<<<(E + 255)/256, 256, 0, stream>>>(ei, deg, E);
    scan_k<<<1, 1024, 0, stream>>>(deg, offs, pos, N);
    fill_k<<<(E + 255)/256, 256, 0, stream>>>(ei, pos, order, E);

    const int tpblocks = (E + 63) / 64;   // 4 waves/block, 16 edges/wave
    edge_fused<<<tpblocks, 256, 0, stream>>>(
        node_s, node_v, edge_s, edge_v, ei,
        B1sh, B1sl, B1vh, B1vl, B2sh, B2sl, B2vh, B2vl,
        Lms, Lmv, m2h, E);

    agg_k<<<(N + 255)/256, 256, 0, stream>>>(m2h, deg, offs, order, agg, N);

    const int ndblocks = ((N + 15)/16 + 3) / 4;   // 4 waves/block, 16 nodes/wave
    node_mfma<<<ndblocks, 256, 0, stream>>>(
        node_s, node_v, agg, B3sh, B3sl, B3vh, B3vl, Lus, Luv, out, N);
}

// Round 10
// 639.532 us; speedup vs baseline: 1.0731x; 1.0018x over previous
//
#include <hip/hip_runtime.h>
#include <math.h>

typedef _Float16 half8 __attribute__((ext_vector_type(8)));
typedef float floatx4 __attribute__((ext_vector_type(4)));

constexpr float C_SS16 = 0.04419417382415922f;  // i2/16
constexpr float C_UNI  = 0.05103103630798288f;  // i3/sqrt(128)
constexpr float C2_SS  = 0.0625f;               // i2/sqrt(128)
constexpr float C2_VS  = 0.07216878364870323f;  // i3/8
constexpr float C_LS   = 0.17677669529663687f;  // 1/sqrt(32)
constexpr float C_LV   = 0.25f;                 // 1/sqrt(16)
constexpr float RS     = 2048.0f;               // residual scale (keeps lo-parts normal in fp16)
constexpr float RSI    = 1.0f / 2048.0f;

// split fp32 -> fp16 hi + SCALED fp16 residual (residual*2048 stays normal-range)
__device__ __forceinline__ void split8s(const float* p, half8& ah, half8& alS) {
#pragma unroll
    for (int j = 0; j < 8; ++j) {
        _Float16 h = (_Float16)p[j];
        ah[j] = h;
        alS[j] = (_Float16)((p[j] - (float)h) * RS);
    }
}
// 3-term split MFMA with separate scaled-residual accumulator
__device__ __forceinline__ void mfma_tri(half8 ah, half8 alS, half8 bh, half8 blS,
                                         floatx4& acc, floatx4& accR) {
    acc  = __builtin_amdgcn_mfma_f32_16x16x32_f16(ah,  bh,  acc,  0, 0, 0);
    accR = __builtin_amdgcn_mfma_f32_16x16x32_f16(alS, bh,  accR, 0, 0, 0);
    accR = __builtin_amdgcn_mfma_f32_16x16x32_f16(ah,  blS, accR, 0, 0, 0);
}

// =====================================================================
// Weight prep: fp32 -> (fp16 hi, fp16 lo*2048) B-fragments, norms folded.
// Grid-stride (88 blocks): per-element math is a pure function of idx.
// =====================================================================
__global__ void prep_w(const float* __restrict__ W1ss, const float* __restrict__ W1sv,
                       const float* __restrict__ W1vs, const float* __restrict__ W1vvs,
                       const float* __restrict__ W1vvv,
                       const float* __restrict__ W2ss, const float* __restrict__ W2sv,
                       const float* __restrict__ W2vs, const float* __restrict__ W2vvs,
                       const float* __restrict__ W2vvv,
                       const float* __restrict__ W3ss, const float* __restrict__ W3sv,
                       const float* __restrict__ W3vs, const float* __restrict__ W3vvs,
                       const float* __restrict__ W3vvv,
                       _Float16* B1sh, _Float16* B1sl, _Float16* B1vh, _Float16* B1vl,
                       _Float16* B2sh, _Float16* B2sl, _Float16* B2vh, _Float16* B2vl,
                       _Float16* B3sh, _Float16* B3sl, _Float16* B3vh, _Float16* B3vl)
{
    const int t0 = blockIdx.x*256 + threadIdx.x;
    const int gs = gridDim.x*256;
    for (int idx = t0; idx < 10*512; idx += gs) {
        int t_k = idx >> 9, lane = (idx >> 3) & 63, j = idx & 7;
        int q = lane >> 4, n = lane & 15;
        int k = t_k*32 + q*8 + j;
        float v;
        if (k < 256) { int i = k>>4, jj = k&15; v = W1ss[(i*16+jj)*16+n] * C_SS16; }
        else { int kk = k-256; int i = kk>>3, jj = kk&7; v = W1vvs[(i*8+jj)*16+n] * C_UNI; }
        _Float16 h = (_Float16)v;
        B1sh[idx] = h; B1sl[idx] = (_Float16)((v - (float)h) * RS);
    }
    for (int idx = t0; idx < 10*512; idx += gs) {
        int t_k = idx >> 9, lane = (idx >> 3) & 63, j = idx & 7;
        int q = lane >> 4, n = lane & 15;
        int k = t_k*32 + q*8 + j;
        float v = 0.f;
        if (n < 8) {
            if (k < 128) { int i = k>>3, jj = k&7; v = W1sv[(i*8+jj)*8+n] * C_UNI; }
            else if (k < 256) { int kk = k-128; int i = kk>>4, jj = kk&15; v = W1vs[(i*16+jj)*8+n] * C_UNI; }
            else { int kk = k-256; int i = kk>>3, jj = kk&7; v = W1vvv[(i*8+jj)*8+n] * C_UNI; }
        }
        _Float16 h = (_Float16)v;
        B1vh[idx] = h; B1vl[idx] = (_Float16)((v - (float)h) * RS);
    }
    for (int idx = t0; idx < 3*6*512; idx += gs) {
        int tn = idx / 3072, t_k = (idx % 3072) >> 9, lane = (idx >> 3) & 63, j = idx & 7;
        int q = lane >> 4, n = lane & 15, col = tn*16 + n;
        int k = t_k*32 + q*8 + j;
        float v;
        if (k < 128) { int i = k>>3, jj = k&7; v = W2ss[(i*8+jj)*48+col] * C2_SS; }
        else { int kk = k-128; int i = kk>>3, jj = kk&7; v = W2vvs[(i*8+jj)*48+col] * C_UNI; }
        _Float16 h = (_Float16)v;
        B2sh[idx] = h; B2sl[idx] = (_Float16)((v - (float)h) * RS);
    }
    for (int idx = t0; idx < 8*512; idx += gs) {
        int t_k = idx >> 9, lane = (idx >> 3) & 63, j = idx & 7;
        int q = lane >> 4, n = lane & 15;
        int k = t_k*32 + q*8 + j;
        float v;
        if (k < 128) { int i = k>>3, jj = k&7; v = W2sv[(i*8+jj)*16+n] * C_UNI; }
        else if (k < 192) { int kk = k-128; int i = kk>>3, jj = kk&7; v = W2vs[(i*8+jj)*16+n] * C2_VS; }
        else { int kk = k-192; int i = kk>>3, jj = kk&7; v = W2vvv[(i*8+jj)*16+n] * C_UNI; }
        _Float16 h = (_Float16)v;
        B2vh[idx] = h; B2vl[idx] = (_Float16)((v - (float)h) * RS);
    }
    for (int idx = t0; idx < 3*10*512; idx += gs) {
        int tn = idx / 5120, rem = idx % 5120;
        int t_k = rem >> 9, lane = (rem >> 3) & 63, j = rem & 7;
        int q = lane >> 4, n = lane & 15, col = tn*16 + n;
        int k = t_k*32 + q*8 + j;
        float v;
        if (k < 256) { int i = k>>4, jj = k&15; v = W3ss[(i*16+jj)*48+col] * C_SS16; }
        else { int kk = k-256; int i = kk>>3, jj = kk&7; v = W3vvs[(i*8+jj)*48+col] * C_UNI; }
        _Float16 h = (_Float16)v;
        B3sh[idx] = h; B3sl[idx] = (_Float16)((v - (float)h) * RS);
    }
    for (int idx = t0; idx < 10*512; idx += gs) {
        int t_k = idx >> 9, lane = (idx >> 3) & 63, j = idx & 7;
        int q = lane >> 4, n = lane & 15;
        int k = t_k*32 + q*8 + j;
        float v;
        if (k < 128) { int i = k>>3, jj = k&7; v = W3sv[(i*8+jj)*16+n] * C_UNI; }
        else if (k < 256) { int kk = k-128; int i = kk>>4, jj = kk&15; v = W3vs[(i*16+jj)*16+n] * C_UNI; }
        else { int kk = k-256; int i = kk>>3, jj = kk&7; v = W3vvv[(i*8+jj)*16+n] * C_UNI; }
        _Float16 h = (_Float16)v;
        B3vh[idx] = h; B3vl[idx] = (_Float16)((v - (float)h) * RS);
    }
}

// =====================================================================
// Fused edge kernel — EXACT R0/R8 structure (harness-verified passing).
// =====================================================================
__global__ __launch_bounds__(256)
void edge_fused(const float* __restrict__ ns, const float* __restrict__ nv,
                const float* __restrict__ edge_s, const float* __restrict__ edge_v,
                const int* __restrict__ ei,
                const _Float16* __restrict__ B1sh, const _Float16* __restrict__ B1sl,
                const _Float16* __restrict__ B1vh, const _Float16* __restrict__ B1vl,
                const _Float16* __restrict__ B2sh, const _Float16* __restrict__ B2sl,
                const _Float16* __restrict__ B2vh, const _Float16* __restrict__ B2vl,
                const float* __restrict__ Lms, const float* __restrict__ Lmv,
                float* __restrict__ m2h, int E)
{
    __shared__ float mT[4][16*41];       // [wave][edge][41] m transpose
    __shared__ float ep[4][2][16*49];    // [wave][{hs,gv}][edge][49]
    const int lane = threadIdx.x & 63;
    const int wv = threadIdx.x >> 6;
    const int e0 = (blockIdx.x*4 + wv) * 16;
    const int q = lane >> 4, n = lane & 15;
    const int e = min(e0 + n, E - 1);
    const int qh = q >> 1, ql = q & 1;
    const int r = ei[e], c2 = ei[E + e];

    // ---------------- stage 1 feature slices ----------------
    float rs_sel[8], rs4[4], rva[2][3], rvs[4][3], csh[8], cv[8][3];
#pragma unroll
    for (int t = 0; t < 8; ++t) rs_sel[t] = ns[(size_t)r*16 + 2*t + qh];
#pragma unroll
    for (int t = 0; t < 4; ++t) rs4[t] = ns[(size_t)r*16 + 4*t + q];
#pragma unroll
    for (int cc = 0; cc < 3; ++cc) {
        rva[0][cc] = nv[(size_t)r*24 + 3*q + cc];
        rva[1][cc] = nv[(size_t)r*24 + 3*(q+4) + cc];
    }
#pragma unroll
    for (int u = 0; u < 4; ++u)
#pragma unroll
        for (int cc = 0; cc < 3; ++cc) rvs[u][cc] = nv[(size_t)r*24 + 3*(2*u+qh) + cc];
    {
        const float4* p = (const float4*)(ns + (size_t)c2*16 + ql*8);
#pragma unroll
        for (int t = 0; t < 2; ++t) { float4 v = p[t]; csh[4*t]=v.x; csh[4*t+1]=v.y; csh[4*t+2]=v.z; csh[4*t+3]=v.w; }
        const float4* pv = (const float4*)(nv + (size_t)c2*24);
        float tmp[24];
#pragma unroll
        for (int t = 0; t < 6; ++t) { float4 v = pv[t]; tmp[4*t]=v.x; tmp[4*t+1]=v.y; tmp[4*t+2]=v.z; tmp[4*t+3]=v.w; }
#pragma unroll
        for (int k = 0; k < 8; ++k) { cv[k][0]=tmp[3*k]; cv[k][1]=tmp[3*k+1]; cv[k][2]=tmp[3*k+2]; }
    }

    const half8* B1sH = (const half8*)B1sh; const half8* B1sL = (const half8*)B1sl;
    const half8* B1vH = (const half8*)B1vh; const half8* B1vL = (const half8*)B1vl;

    // ---- stage1 scalar GEMM: [16e x 320] @ [320 x 16] ----
    {
        floatx4 acc = {0.f,0.f,0.f,0.f}, accR = {0.f,0.f,0.f,0.f};
#pragma unroll
        for (int t = 0; t < 10; ++t) {
            float p[8];
            if (t < 8) {
                const float m = rs_sel[t];
#pragma unroll
                for (int j = 0; j < 8; ++j) p[j] = m * csh[j];
            } else {
                const int u = t - 8;
                const float vx = rva[u][0], vy = rva[u][1], vz = rva[u][2];
#pragma unroll
                for (int j = 0; j < 8; ++j) p[j] = fmaf(vx, cv[j][0], fmaf(vy, cv[j][1], vz*cv[j][2]));
            }
            half8 ah, al; split8s(p, ah, al);
            mfma_tri(ah, al, B1sH[t*64 + lane], B1sL[t*64 + lane], acc, accR);
        }
#pragma unroll
        for (int r2 = 0; r2 < 4; ++r2)
            mT[wv][(q*4 + r2)*41 + n] = acc[r2] + accR[r2]*RSI;
    }
    // ---- stage1 vector GEMMs per component ----
#pragma unroll 1
    for (int c = 0; c < 3; ++c) {
        const int c1 = (c+1)%3, c2i = (c+2)%3;
        floatx4 acc = {0.f,0.f,0.f,0.f}, accR = {0.f,0.f,0.f,0.f};
#pragma unroll
        for (int t = 0; t < 10; ++t) {
            float p[8];
            if (t < 4) {
                const float m = rs4[t];
#pragma unroll
                for (int j = 0; j < 8; ++j) p[j] = m * cv[j][c];
            } else if (t < 8) {
                const float m = rvs[t-4][c];
#pragma unroll
                for (int j = 0; j < 8; ++j) p[j] = m * csh[j];
            } else {
                const int u = t - 8;
                const float v1 = rva[u][c1], v2 = rva[u][c2i];
#pragma unroll
                for (int j = 0; j < 8; ++j) p[j] = v1*cv[j][c2i] - v2*cv[j][c1];
            }
            half8 ah, al; split8s(p, ah, al);
            mfma_tri(ah, al, B1vH[t*64 + lane], B1vL[t*64 + lane], acc, accR);
        }
        if (n < 8) {
#pragma unroll
            for (int r2 = 0; r2 < 4; ++r2)
                mT[wv][(q*4 + r2)*41 + 16 + 3*n + c] = acc[r2] + accR[r2]*RSI;
        }
    }
    __syncthreads();

    // ---------------- stage 2 inputs ----------------
    float msr[4], mva[2][3], es[8], ev[8][3];
#pragma unroll
    for (int t = 0; t < 4; ++t) msr[t] = mT[wv][n*41 + 4*t + q];
#pragma unroll
    for (int u = 0; u < 2; ++u)
#pragma unroll
        for (int cc = 0; cc < 3; ++cc) mva[u][cc] = mT[wv][n*41 + 16 + 3*(4*u+q) + cc];
    {
        const float4* p = (const float4*)(edge_s + (size_t)e*8);
#pragma unroll
        for (int t = 0; t < 2; ++t) { float4 v = p[t]; es[4*t]=v.x; es[4*t+1]=v.y; es[4*t+2]=v.z; es[4*t+3]=v.w; }
        const float4* pv = (const float4*)(edge_v + (size_t)e*24);
        float tmp[24];
#pragma unroll
        for (int t = 0; t < 6; ++t) { float4 v = pv[t]; tmp[4*t]=v.x; tmp[4*t+1]=v.y; tmp[4*t+2]=v.z; tmp[4*t+3]=v.w; }
#pragma unroll
        for (int k = 0; k < 8; ++k) { ev[k][0]=tmp[3*k]; ev[k][1]=tmp[3*k+1]; ev[k][2]=tmp[3*k+2]; }
    }

    const half8* B2sH = (const half8*)B2sh; const half8* B2sL = (const half8*)B2sl;
    const half8* B2vH = (const half8*)B2vh; const half8* B2vL = (const half8*)B2vl;

    // ---- stage2 scalar GEMM: [16e x 192] @ [192 x 48] ----
    floatx4 accs[3], accsR[3];
#pragma unroll
    for (int t = 0; t < 3; ++t) { accs[t] = (floatx4){0.f,0.f,0.f,0.f}; accsR[t] = (floatx4){0.f,0.f,0.f,0.f}; }
#pragma unroll
    for (int t = 0; t < 6; ++t) {
        float p[8];
        if (t < 4) {
            const float m = msr[t];
#pragma unroll
            for (int j = 0; j < 8; ++j) p[j] = m * es[j];
        } else {
            const int u = t - 4;
            const float vx = mva[u][0], vy = mva[u][1], vz = mva[u][2];
#pragma unroll
            for (int j = 0; j < 8; ++j) p[j] = fmaf(vx, ev[j][0], fmaf(vy, ev[j][1], vz*ev[j][2]));
        }
        half8 ah, al; split8s(p, ah, al);
#pragma unroll
        for (int tn = 0; tn < 3; ++tn)
            mfma_tri(ah, al, B2sH[(tn*6 + t)*64 + lane], B2sL[(tn*6 + t)*64 + lane], accs[tn], accsR[tn]);
    }

    float* hsL = &ep[wv][0][0];
    float* gvL = &ep[wv][1][0];
#pragma unroll
    for (int t = 0; t < 3; ++t)
#pragma unroll
        for (int r2 = 0; r2 < 4; ++r2) {
            const int row = q*4 + r2;
            const float v = accs[t][r2] + accsR[t][r2]*RSI;
            if (t < 2) hsL[row*49 + t*16 + n] = v / (1.f + __expf(-v)) * C_LS;
            else       hsL[row*49 + 32 + n] = v;
        }
    __syncthreads();

    // scalar epilogue
    {
        float os[4] = {0.f, 0.f, 0.f, 0.f};
#pragma unroll 4
        for (int s = 0; s < 32; ++s) {
            const float hv_ = hsL[n*49 + s];
            const float4 w = *(const float4*)(Lms + s*16 + 4*q);
            os[0] = fmaf(hv_, w.x, os[0]); os[1] = fmaf(hv_, w.y, os[1]);
            os[2] = fmaf(hv_, w.z, os[2]); os[3] = fmaf(hv_, w.w, os[3]);
        }
        if (e0 + n < E) {
#pragma unroll
            for (int u = 0; u < 4; ++u)
                m2h[(size_t)(e0 + n)*40 + 4*q + u] = os[u];
        }
    }

    // ---- stage2 vector GEMMs ----
    floatx4 accv[3];
#pragma unroll 1
    for (int c = 0; c < 3; ++c) {
        const int c1 = (c+1)%3, c2i = (c+2)%3;
        floatx4 acc = {0.f,0.f,0.f,0.f}, accR = {0.f,0.f,0.f,0.f};
#pragma unroll
        for (int t = 0; t < 8; ++t) {
            float p[8];
            if (t < 4) {
                const float m = msr[t];
#pragma unroll
                for (int j = 0; j < 8; ++j) p[j] = m * ev[j][c];
            } else if (t < 6) {
                const float m = mva[t-4][c];
#pragma unroll
                for (int j = 0; j < 8; ++j) p[j] = m * es[j];
            } else {
                const int u = t - 6;
                const float v1 = mva[u][c1], v2 = mva[u][c2i];
#pragma unroll
                for (int j = 0; j < 8; ++j) p[j] = v1*ev[j][c2i] - v2*ev[j][c1];
            }
            half8 ah, al; split8s(p, ah, al);
            mfma_tri(ah, al, B2vH[t*64 + lane], B2vL[t*64 + lane], acc, accR);
        }
#pragma unroll
        for (int r2 = 0; r2 < 4; ++r2) acc[r2] = acc[r2] + accR[r2]*RSI;
        accv[c] = acc;
    }
#pragma unroll
    for (int r2 = 0; r2 < 4; ++r2) {
        const int row = q*4 + r2;
        const float gt = C_LV / (1.f + __expf(-hsL[row*49 + 32 + n]));
#pragma unroll
        for (int c = 0; c < 3; ++c) gvL[row*49 + c*16 + n] = accv[c][r2] * gt;
    }
    __syncthreads();

    // vector epilogue
    {
        float ov[3][2] = {{0.f,0.f},{0.f,0.f},{0.f,0.f}};
#pragma unroll 4
        for (int k = 0; k < 16; ++k) {
            const float2 w = *(const float2*)(Lmv + k*8 + 2*q);
#pragma unroll
            for (int c = 0; c < 3; ++c) {
                const float gv = gvL[n*49 + c*16 + k];
                ov[c][0] = fmaf(gv, w.x, ov[c][0]);
                ov[c][1] = fmaf(gv, w.y, ov[c][1]);
            }
        }
        if (e0 + n < E) {
#pragma unroll
            for (int o2 = 0; o2 < 2; ++o2)
#pragma unroll
                for (int c = 0; c < 3; ++c)
                    m2h[(size_t)(e0 + n)*40 + 16 + 3*(2*q + o2) + c] = ov[c][o2];
        }
    }
}

// =====================================================================
// CSR build
// =====================================================================
__global__ void hist_k(const int* __restrict__ ei, int* __restrict__ deg, int E) {
    const int e = blockIdx.x*256 + threadIdx.x;
    if (e < E) atomicAdd(&deg[ei[E + e]], 1);
}
__global__ void scan_k(const int* __restrict__ deg, int* __restrict__ offs,
                       int* __restrict__ pos, int N) {
    __shared__ int sm[1024];
    const int t = threadIdx.x;
    const int chunk = (N + 1023) / 1024;
    const int lo = t * chunk, hi = min(lo + chunk, N);
    int s = 0;
    for (int i = lo; i < hi; ++i) s += deg[i];
    sm[t] = s; __syncthreads();
    for (int off = 1; off < 1024; off <<= 1) {
        int v = (t >= off) ? sm[t - off] : 0;
        __syncthreads();
        sm[t] += v;
        __syncthreads();
    }
    int base = sm[t] - s;
    for (int i = lo; i < hi; ++i) { offs[i] = base; pos[i] = base; base += deg[i]; }
}
__global__ void fill_k(const int* __restrict__ ei, int* __restrict__ pos,
                       int* __restrict__ order, int E) {
    const int e = blockIdx.x*256 + threadIdx.x;
    if (e < E) { int p = atomicAdd(&pos[ei[E + e]], 1); order[p] = e; }
}

// =====================================================================
// agg_k: CSR gather-aggregate fp32 messages -> agg[N][40]  (R0-exact)
// =====================================================================
__global__ __launch_bounds__(256)
void agg_k(const float* __restrict__ m2h,
           const int* __restrict__ deg, const int* __restrict__ offs,
           const int* __restrict__ order,
           float* __restrict__ agg, int N)
{
    const int n = blockIdx.x*256 + threadIdx.x;
    if (n >= N) return;
    float a[40];
#pragma unroll
    for (int u = 0; u < 40; ++u) a[u] = 0.f;
    const int cnt = deg[n], base = offs[n];
    for (int t = 0; t < cnt; ++t) {
        const int id = order[base + t];
        const float4* mp = (const float4*)(m2h + (size_t)id*40);
#pragma unroll
        for (int u = 0; u < 10; ++u) {
            float4 v = mp[u];
            a[4*u] += v.x; a[4*u+1] += v.y; a[4*u+2] += v.z; a[4*u+3] += v.w;
        }
    }
    float4* o = (float4*)(agg + (size_t)n*40);
#pragma unroll
    for (int u = 0; u < 10; ++u) o[u] = make_float4(a[4*u], a[4*u+1], a[4*u+2], a[4*u+3]);
}

// =====================================================================
// node_mfma: TP(node, agg) via split-MFMA + gate + linear -> out[N,40]
// EXACT R0 structure.
// =====================================================================
__global__ __launch_bounds__(256)
void node_mfma(const float* __restrict__ ns, const float* __restrict__ nv,
               const float* __restrict__ agg,
               const _Float16* __restrict__ B3sh, const _Float16* __restrict__ B3sl,
               const _Float16* __restrict__ B3vh, const _Float16* __restrict__ B3vl,
               const float* __restrict__ Lus, const float* __restrict__ Luv,
               float* __restrict__ out, int N)
{
    __shared__ float ep[4][2][16*49];    // [wave][{hs,gv}][node][49]
    const int lane = threadIdx.x & 63;
    const int wv = threadIdx.x >> 6;
    const int n0 = (blockIdx.x*4 + wv) * 16;
    const int q = lane >> 4, n = lane & 15;
    const int nd = min(n0 + n, N - 1);
    const int qh = q >> 1, ql = q & 1;

    // row side = node features
    float rs_sel[8], rs4[4], rva[2][3], rvs[4][3];
#pragma unroll
    for (int t = 0; t < 8; ++t) rs_sel[t] = ns[(size_t)nd*16 + 2*t + qh];
#pragma unroll
    for (int t = 0; t < 4; ++t) rs4[t] = ns[(size_t)nd*16 + 4*t + q];
#pragma unroll
    for (int cc = 0; cc < 3; ++cc) {
        rva[0][cc] = nv[(size_t)nd*24 + 3*q + cc];
        rva[1][cc] = nv[(size_t)nd*24 + 3*(q+4) + cc];
    }
#pragma unroll
    for (int u = 0; u < 4; ++u)
#pragma unroll
        for (int cc = 0; cc < 3; ++cc) rvs[u][cc] = nv[(size_t)nd*24 + 3*(2*u+qh) + cc];
    // col side = aggregated features
    float csh[8], cv[8][3];
    {
        const float4* p = (const float4*)(agg + (size_t)nd*40 + ql*8);
#pragma unroll
        for (int t = 0; t < 2; ++t) { float4 v = p[t]; csh[4*t]=v.x; csh[4*t+1]=v.y; csh[4*t+2]=v.z; csh[4*t+3]=v.w; }
        const float4* pv = (const float4*)(agg + (size_t)nd*40 + 16);
        float tmp[24];
#pragma unroll
        for (int t = 0; t < 6; ++t) { float4 v = pv[t]; tmp[4*t]=v.x; tmp[4*t+1]=v.y; tmp[4*t+2]=v.z; tmp[4*t+3]=v.w; }
#pragma unroll
        for (int k = 0; k < 8; ++k) { cv[k][0]=tmp[3*k]; cv[k][1]=tmp[3*k+1]; cv[k][2]=tmp[3*k+2]; }
    }

    const half8* B3sH = (const half8*)B3sh; const half8* B3sL = (const half8*)B3sl;
    const half8* B3vH = (const half8*)B3vh; const half8* B3vL = (const half8*)B3vl;

    // ---- scalar GEMM: [16n x 320] @ [320 x 48] ----
    floatx4 accs[3], accsR[3];
#pragma unroll
    for (int t = 0; t < 3; ++t) { accs[t] = (floatx4){0.f,0.f,0.f,0.f}; accsR[t] = (floatx4){0.f,0.f,0.f,0.f}; }
#pragma unroll
    for (int t = 0; t < 10; ++t) {
        float p[8];
        if (t < 8) {
            const float m = rs_sel[t];
#pragma unroll
            for (int j = 0; j < 8; ++j) p[j] = m * csh[j];
        } else {
            const int u = t - 8;
            const float vx = rva[u][0], vy = rva[u][1], vz = rva[u][2];
#pragma unroll
            for (int j = 0; j < 8; ++j) p[j] = fmaf(vx, cv[j][0], fmaf(vy, cv[j][1], vz*cv[j][2]));
        }
        half8 ah, al; split8s(p, ah, al);
#pragma unroll
        for (int tn = 0; tn < 3; ++tn)
            mfma_tri(ah, al, B3sH[(tn*10 + t)*64 + lane], B3sL[(tn*10 + t)*64 + lane], accs[tn], accsR[tn]);
    }

    float* hsL = &ep[wv][0][0];
    float* gvL = &ep[wv][1][0];
#pragma unroll
    for (int t = 0; t < 3; ++t)
#pragma unroll
        for (int r2 = 0; r2 < 4; ++r2) {
            const int row = q*4 + r2;
            const float v = accs[t][r2] + accsR[t][r2]*RSI;
            if (t < 2) hsL[row*49 + t*16 + n] = v / (1.f + __expf(-v)) * C_LS;
            else       hsL[row*49 + 32 + n] = v;
        }
    __syncthreads();

    // scalar epilogue -> out[:, 0:16]
    {
        float os[4] = {0.f, 0.f, 0.f, 0.f};
#pragma unroll 4
        for (int s = 0; s < 32; ++s) {
            const float hv_ = hsL[n*49 + s];
            const float4 w = *(const float4*)(Lus + s*16 + 4*q);
            os[0] = fmaf(hv_, w.x, os[0]); os[1] = fmaf(hv_, w.y, os[1]);
            os[2] = fmaf(hv_, w.z, os[2]); os[3] = fmaf(hv_, w.w, os[3]);
        }
        if (n0 + n < N) {
#pragma unroll
            for (int u = 0; u < 4; ++u)
                out[(size_t)(n0 + n)*40 + 4*q + u] = os[u];
        }
    }

    // ---- vector GEMMs per component: [16n x 320] @ [320 x 16] ----
    floatx4 accv[3];
#pragma unroll 1
    for (int c = 0; c < 3; ++c) {
        const int c1 = (c+1)%3, c2i = (c+2)%3;
        floatx4 acc = {0.f,0.f,0.f,0.f}, accR = {0.f,0.f,0.f,0.f};
#pragma unroll
        for (int t = 0; t < 10; ++t) {
            float p[8];
            if (t < 4) {
                const float m = rs4[t];
#pragma unroll
                for (int j = 0; j < 8; ++j) p[j] = m * cv[j][c];
            } else if (t < 8) {
                const float m = rvs[t-4][c];
#pragma unroll
                for (int j = 0; j < 8; ++j) p[j] = m * csh[j];
            } else {
                const int u = t - 8;
                const float v1 = rva[u][c1], v2 = rva[u][c2i];
#pragma unroll
                for (int j = 0; j < 8; ++j) p[j] = v1*cv[j][c2i] - v2*cv[j][c1];
            }
            half8 ah, al; split8s(p, ah, al);
            mfma_tri(ah, al, B3vH[t*64 + lane], B3vL[t*64 + lane], acc, accR);
        }
#pragma unroll
        for (int r2 = 0; r2 < 4; ++r2) acc[r2] = acc[r2] + accR[r2]*RSI;
        accv[c] = acc;
    }
#pragma unroll
    for (int r2 = 0; r2 < 4; ++r2) {
        const int row = q*4 + r2;
        const float gt = C_LV / (1.f + __expf(-hsL[row*49 + 32 + n]));
#pragma unroll
        for (int c = 0; c < 3; ++c) gvL[row*49 + c*16 + n] = accv[c][r2] * gt;
    }
    __syncthreads();

    // vector epilogue -> out[:, 16:40]
    {
        float ov[3][2] = {{0.f,0.f},{0.f,0.f},{0.f,0.f}};
#pragma unroll 4
        for (int k = 0; k < 16; ++k) {
            const float2 w = *(const float2*)(Luv + k*8 + 2*q);
#pragma unroll
            for (int c = 0; c < 3; ++c) {
                const float gv = gvL[n*49 + c*16 + k];
                ov[c][0] = fmaf(gv, w.x, ov[c][0]);
                ov[c][1] = fmaf(gv, w.y, ov[c][1]);
            }
        }
        if (n0 + n < N) {
#pragma unroll
            for (int o2 = 0; o2 < 2; ++o2)
#pragma unroll
                for (int c = 0; c < 3; ++c)
                    out[(size_t)(n0 + n)*40 + 16 + 3*(2*q + o2) + c] = ov[c][o2];
        }
    }
}

// =====================================================================
extern "C" void kernel_launch(void* const* d_in, const int* in_sizes, int n_in,
                              void* d_out, int out_size, void* d_ws, size_t ws_size,
                              hipStream_t stream) {
    const float* node_s = (const float*)d_in[0];
    const float* node_v = (const float*)d_in[1];
    const float* edge_s = (const float*)d_in[3];
    const float* edge_v = (const float*)d_in[4];
    const int*   ei     = (const int*)d_in[5];
    const float* W1ss = (const float*)d_in[6];
    const float* W1sv = (const float*)d_in[7];
    const float* W1vs = (const float*)d_in[8];
    const float* W1vvs= (const float*)d_in[9];
    const float* W1vvv= (const float*)d_in[10];
    const float* W2ss = (const float*)d_in[11];
    const float* W2sv = (const float*)d_in[12];
    const float* W2vs = (const float*)d_in[13];
    const float* W2vvs= (const float*)d_in[14];
    const float* W2vvv= (const float*)d_in[15];
    const float* Lms  = (const float*)d_in[16];
    const float* Lmv  = (const float*)d_in[17];
    const float* W3ss = (const float*)d_in[18];
    const float* W3sv = (const float*)d_in[19];
    const float* W3vs = (const float*)d_in[20];
    const float* W3vvs= (const float*)d_in[21];
    const float* W3vvv= (const float*)d_in[22];
    const float* Lus  = (const float*)d_in[23];
    const float* Luv  = (const float*)d_in[24];

    float* out = (float*)d_out;
    const int N = in_sizes[0] / 16;
    const int E = in_sizes[5] / 2;

    // ws layout: fp16 B-frags, fp32 messages, fp32 agg, CSR ints
    _Float16* B1sh = (_Float16*)d_ws;             // 5120
    _Float16* B1sl = B1sh + 5120;
    _Float16* B1vh = B1sl + 5120;
    _Float16* B1vl = B1vh + 5120;
    _Float16* B2sh = B1vl + 5120;                 // 9216
    _Float16* B2sl = B2sh + 9216;
    _Float16* B2vh = B2sl + 9216;                 // 4096
    _Float16* B2vl = B2vh + 4096;
    _Float16* B3sh = B2vl + 4096;                 // 15360
    _Float16* B3sl = B3sh + 15360;
    _Float16* B3vh = B3sl + 15360;                // 5120
    _Float16* B3vl = B3vh + 5120;                 // ends at 88064 halves = 176128 B
    float* m2h = (float*)((char*)d_ws + 176128);  // [E][40] fp32
    float* agg = m2h + (size_t)40*E;              // [N][40] fp32
    int* deg   = (int*)(agg + (size_t)40*N);      // N
    int* offs  = deg + N;
    int* pos   = offs + N;
    int* order = pos + N;                         // E

    hipMemsetAsync(deg, 0, (size_t)N * sizeof(int), stream);

    prep_w<<<88, 256, 0, stream>>>(W1ss, W1sv, W1vs, W1vvs, W1vvv,
                                   W2ss, W2sv, W2vs, W2vvs, W2vvv,
                                   W3ss, W3sv, W3vs, W3vvs, W3vvv,
                                   B1sh, B1sl, B1vh, B1vl, B2sh, B2sl, B2vh, B2vl,
                                   B3sh, B3sl, B3vh, B3vl);

    hist_k<<<(E + 255)/256, 256, 0, stream>>>(ei, deg, E);
    scan_k<<<1, 1024, 0, stream>>>(deg, offs, pos, N);
    fill_k<<<(E + 255)/256, 256, 0, stream>>>(ei, pos, order, E);

    const int tpblocks = (E + 63) / 64;   // 4 waves/block, 16 edges/wave
    edge_fused<<<tpblocks, 256, 0, stream>>>(
        node_s, node_v, edge_s, edge_v, ei,
        B1sh, B1sl, B1vh, B1vl, B2sh, B2sl, B2vh, B2vl,
        Lms, Lmv, m2h, E);

    agg_k<<<(N + 255)/256, 256, 0, stream>>>(m2h, deg, offs, order, agg, N);

    const int ndblocks = ((N + 15)/16 + 3) / 4;   // 4 waves/block, 16 nodes/wave
    node_mfma<<<ndblocks, 256, 0, stream>>>(
        node_s, node_v, agg, B3sh, B3sl, B3vh, B3vl, Lus, Luv, out, N);
}